// Round 14
// baseline (378.533 us; speedup 1.0000x reference)
//
#include <hip/hip_runtime.h>
#include <stdint.h>

typedef __bf16 bf16x8 __attribute__((ext_vector_type(8)));
typedef float f32x4 __attribute__((ext_vector_type(4)));
typedef float f32x16 __attribute__((ext_vector_type(16)));
typedef unsigned short u16;
typedef u16 u16x8 __attribute__((ext_vector_type(8)));
typedef u16 u16x4 __attribute__((ext_vector_type(4)));
typedef uint32_t u32;

#define DEV __device__ __forceinline__
#define MFMA(a, b, c) __builtin_amdgcn_mfma_f32_16x16x32_bf16(a, b, c, 0, 0, 0)
#define MFMA32(a, b, c) __builtin_amdgcn_mfma_f32_32x32x16_bf16(a, b, c, 0, 0, 0)

static constexpr int B_ = 4, S_ = 2048, M_ = 8192, D_ = 1024, H_ = 16, DFF_ = 4096;

DEV u16 f2bf(float f) {
    union { float f; u32 u; } c; c.f = f;
    u32 u = c.u;
    return (u16)((u + 0x7fffu + ((u >> 16) & 1u)) >> 16);
}

DEV float bf2f(u16 v) {
    union { u32 u; float f; } c; c.u = (u32)v << 16;
    return c.f;
}

DEV u32 cvt_pk_bf16(float lo, float hi) {
    u32 r;
    asm("v_cvt_pk_bf16_f32 %0, %1, %2" : "=v"(r) : "v"(lo), "v"(hi));
    return r;
}

DEV float v_exp2(float x) {  // raw 2^x
    float r;
    asm("v_exp_f32 %0, %1" : "=v"(r) : "v"(x));
    return r;
}

DEV void gload16(void* lds, const void* g) {
    __builtin_amdgcn_global_load_lds(
        (const __attribute__((address_space(1))) unsigned int*)g,
        (__attribute__((address_space(3))) unsigned int*)lds, 16, 0, 0);
}

// ---------------- pre-pass kernels ----------------

// fused: pack mask bits + per-row tile-allones bitmap (wave per row)
__global__ __launch_bounds__(256) void k_pack_amask(const int* __restrict__ m,
                                                    u32* __restrict__ bits,
                                                    u32* __restrict__ am) {
    const int lane = threadIdx.x & 63, wv = threadIdx.x >> 6;
    const int row = blockIdx.x * 4 + wv;
    const int4* s = (const int4*)(m + ((size_t)row * 64 + lane) * 32);
    u32 r = 0;
#pragma unroll
    for (int j = 0; j < 8; j++) {
        int4 v = s[j];
        r |= (u32)(v.x != 0) << (j * 4) | (u32)(v.y != 0) << (j * 4 + 1) |
             (u32)(v.z != 0) << (j * 4 + 2) | (u32)(v.w != 0) << (j * 4 + 3);
    }
    bits[(size_t)row * 64 + lane] = r;
    unsigned long long b = __ballot(r == 0xffffffffu);
    if (lane == 0) {
        u32 a = 0;
#pragma unroll
        for (int t = 0; t < 32; t++)
            a |= (u32)(((b >> (2 * t)) & 3ull) == 3ull) << t;
        am[row] = a;
    }
}

__global__ __launch_bounds__(256) void k_cast_bf16(const float* __restrict__ s,
                                                   u16* __restrict__ d, int n4) {
    int i = blockIdx.x * 256 + threadIdx.x;
    if (i >= n4) return;
    f32x4 v = ((const f32x4*)s)[i];
    u16x4 o;
    o[0] = f2bf(v[0]); o[1] = f2bf(v[1]); o[2] = f2bf(v[2]); o[3] = f2bf(v[3]);
    ((u16x4*)d)[i] = o;
}

// src [K][N] f32 -> dst [N][K] bf16
__global__ void k_transpose_cast(const float* __restrict__ s, u16* __restrict__ d,
                                 int K, int N) {
    __shared__ float t[32][33];
    int n0 = blockIdx.x * 32, k0 = blockIdx.y * 32;
    int tx = threadIdx.x, ty = threadIdx.y;
#pragma unroll
    for (int i = 0; i < 4; i++)
        t[ty + i * 8][tx] = s[(size_t)(k0 + ty + i * 8) * N + n0 + tx];
    __syncthreads();
#pragma unroll
    for (int i = 0; i < 4; i++)
        d[(size_t)(n0 + ty + i * 8) * K + k0 + tx] = f2bf(t[tx][ty + i * 8]);
}

// four DxD transposes in one launch
__global__ void k_transpose_cast4(const float* __restrict__ s0,
                                  const float* __restrict__ s1,
                                  const float* __restrict__ s2,
                                  const float* __restrict__ s3,
                                  u16* __restrict__ dbase) {
    __shared__ float t[32][33];
    const int z = blockIdx.z;
    const float* s = (z == 0) ? s0 : (z == 1) ? s1 : (z == 2) ? s2 : s3;
    u16* d = dbase + (size_t)z * D_ * D_;
    int n0 = blockIdx.x * 32, k0 = blockIdx.y * 32;
    int tx = threadIdx.x, ty = threadIdx.y;
#pragma unroll
    for (int i = 0; i < 4; i++)
        t[ty + i * 8][tx] = s[(size_t)(k0 + ty + i * 8) * D_ + n0 + tx];
    __syncthreads();
#pragma unroll
    for (int i = 0; i < 4; i++)
        d[(size_t)(n0 + ty + i * 8) * D_ + k0 + tx] = f2bf(t[tx][ty + i * 8]);
}

// ---- 128x128 8-wave GEMM, BK=64, dbuf LDS, counted vmcnt, T2 swizzle ----
// EPI 0: QKV scatter via LDS-coalesced epilogue (Q scaled; V transposed to Vt)
// EPI 1: +bf16 resid, bf16 out; EPI 2: +bias relu bf16
template <int EPI>
__global__ __launch_bounds__(512, 4) void k_gemm8(const u16* __restrict__ A,
                                                  const u16* __restrict__ Bt,
                                                  u16* __restrict__ Cb,
                                                  const float* __restrict__ bias,
                                                  const u16* __restrict__ residb,
                                                  u16* __restrict__ Vt,
                                                  int N, int K) {
    __shared__ u16 smem[32768];  // 64KB: As dbuf | Bs dbuf; reused as C-tile in EPI0
    u16* As0 = smem;             // As[buf] = As0 + buf*8192
    u16* Bs0 = smem + 16384;     // Bs[buf] = Bs0 + buf*8192
    const int tid = threadIdx.x, lane = tid & 63, wave = tid >> 6;
    const int lr = lane & 15, lg = lane >> 4;
    const int wm = wave >> 1, wn = wave & 1;
    const int nbx = N >> 7;
    const int chunk = gridDim.x >> 3;
    const int id = ((int)blockIdx.x & 7) * chunk + ((int)blockIdx.x >> 3);
    const size_t row0 = (size_t)(id / nbx) * 128;
    const int col0 = (id % nbx) * 128;
    const int srow = lane >> 3;
    const int sgr = (lane & 7) ^ srow;
    const int NT = K >> 6;
    f32x4 acc[2][4] = {};

    auto stage = [&](int buf, int t) {
#pragma unroll
        for (int i = 0; i < 2; i++) {
            int c = i * 8 + wave;
            gload16((char*)(As0 + buf * 8192) + c * 1024,
                    (const char*)(A + (row0 + c * 8 + srow) * K + t * 64 + sgr * 8));
        }
#pragma unroll
        for (int i = 0; i < 2; i++) {
            int c = i * 8 + wave;
            gload16((char*)(Bs0 + buf * 8192) + c * 1024,
                    (const char*)(Bt + (size_t)(col0 + c * 8 + srow) * K + t * 64 + sgr * 8));
        }
    };

    stage(0, 0);
    for (int t = 0; t < NT; ++t) {
        const int cur = t & 1;
        if (t + 1 < NT) {
            stage(cur ^ 1, t + 1);
            asm volatile("s_waitcnt vmcnt(4)" ::: "memory");
        } else {
            asm volatile("s_waitcnt vmcnt(0)" ::: "memory");
        }
        __builtin_amdgcn_s_barrier();
        asm volatile("" ::: "memory");
        bf16x8 bF[4][2];
#pragma unroll
        for (int n = 0; n < 4; n++) {
            int r = wn * 64 + n * 16 + lr;
            int rb = r * 128, sw = (r & 7) << 4;
#pragma unroll
            for (int ks = 0; ks < 2; ks++)
                bF[n][ks] = *(const bf16x8*)((char*)(Bs0 + cur * 8192) +
                                             (rb + ((ks * 64 + lg * 16) ^ sw)));
        }
#pragma unroll
        for (int m = 0; m < 2; m++) {
            int r = wm * 32 + m * 16 + lr;
            int rb = r * 128, sw = (r & 7) << 4;
            bf16x8 a0 = *(const bf16x8*)((char*)(As0 + cur * 8192) + (rb + ((lg * 16) ^ sw)));
            bf16x8 a1 = *(const bf16x8*)((char*)(As0 + cur * 8192) + (rb + ((64 + lg * 16) ^ sw)));
            __builtin_amdgcn_s_setprio(1);
#pragma unroll
            for (int n = 0; n < 4; n++) {
                acc[m][n] = MFMA(a0, bF[n][0], acc[m][n]);
                acc[m][n] = MFMA(a1, bF[n][1], acc[m][n]);
            }
            __builtin_amdgcn_s_setprio(0);
        }
        asm volatile("" ::: "memory");
        __builtin_amdgcn_s_barrier();
    }
    if constexpr (EPI == 0) {
        // LDS-coalesced scatter. proj/heads uniform per block (128 | 1024).
        const int proj = col0 >> 10;
        const int hloc0 = (col0 >> 6) & 15;
        const int b = (int)(row0 >> 11);
        const int s0g = (int)(row0 & 2047);
        const float sc = (proj == 0) ? 0.1803368801111832f : 1.f;
        if (proj < 2) {
            // direct layout: Cs[s_local][cg_local], stride 136
#pragma unroll
            for (int m = 0; m < 2; m++)
#pragma unroll
                for (int n = 0; n < 4; n++) {
                    int cgl = wn * 64 + n * 16 + lr;
                    int sl0 = wm * 32 + m * 16 + lg * 4;
#pragma unroll
                    for (int i = 0; i < 4; i++)
                        smem[(sl0 + i) * 136 + cgl] = f2bf(acc[m][n][i] * sc);
                }
            __syncthreads();
#pragma unroll
            for (int j = 0; j < 4; j++) {
                int c = tid + j * 512;      // 0..2047
                int sl = c >> 4;            // s_local 0..127
                int cc = c & 15;            // col chunk (8 u16)
                u16x8 vv = *(const u16x8*)&smem[sl * 136 + cc * 8];
                int hh = hloc0 + (cc >> 3);
                int dk = (cc & 7) * 8;
                *(u16x8*)(Cb + ((size_t)(proj * 64 + b * 16 + hh) * 2048 + s0g + sl) * 64 + dk) = vv;
            }
        } else {
            // V: transposed layout Cs[cg_local][s_local], stride 136
#pragma unroll
            for (int m = 0; m < 2; m++)
#pragma unroll
                for (int n = 0; n < 4; n++) {
                    int cgl = wn * 64 + n * 16 + lr;
                    int sl0 = wm * 32 + m * 16 + lg * 4;
                    u16x4 ov;
#pragma unroll
                    for (int i = 0; i < 4; i++) ov[i] = f2bf(acc[m][n][i]);
                    *(u16x4*)&smem[cgl * 136 + sl0] = ov;
                }
            __syncthreads();
#pragma unroll
            for (int j = 0; j < 4; j++) {
                int c = tid + j * 512;
                int cgl = c >> 4;           // 0..127
                int scn = c & 15;           // s chunk (8 u16)
                u16x8 vv = *(const u16x8*)&smem[cgl * 136 + scn * 8];
                int hh = hloc0 + (cgl >> 6);
                int dk = cgl & 63;
                *(u16x8*)(Vt + ((size_t)(b * 16 + hh) * 64 + dk) * 2048 + s0g + scn * 8) = vv;
            }
        }
    } else {
#pragma unroll
        for (int m = 0; m < 2; m++)
#pragma unroll
            for (int n = 0; n < 4; n++) {
                const int cg = col0 + wn * 64 + n * 16 + lr;
                const int rbase = (int)row0 + wm * 32 + m * 16 + lg * 4;
#pragma unroll
                for (int i = 0; i < 4; i++) {
                    const int rg = rbase + i;
                    float v = acc[m][n][i];
                    if constexpr (EPI == 1) {
                        Cb[(size_t)rg * N + cg] =
                            f2bf(v + bf2f(residb[(size_t)rg * N + cg]));
                    } else {
                        v += bias[cg];
                        v = v > 0.f ? v : 0.f;
                        Cb[(size_t)rg * N + cg] = f2bf(v);
                    }
                }
            }
    }
}

// ---- 256x256 8-wave 4-phase GEMM, BK=64, dbuf LDS, counted vmcnt ----
// EPI 2: +bias relu bf16 ; EPI 3: bf16 split-K partial store
template <int EPI, int KSPLITS>
__global__ __launch_bounds__(512, 2) void k_gemm256(const u16* __restrict__ A,
                                                    const u16* __restrict__ Bt,
                                                    u16* __restrict__ Cb,
                                                    u16* __restrict__ Cb2,
                                                    const float* __restrict__ bias,
                                                    int N, int Keff, int lda) {
    __shared__ u16 As[2][256 * 64];
    __shared__ u16 Bs[2][256 * 64];
    const int tid = threadIdx.x, lane = tid & 63, wave = tid >> 6;
    const int lr = lane & 15, lg = lane >> 4;
    const int wm = wave >> 2, wn = wave & 3;
    const int nbx = N >> 8;
    const int chunk = gridDim.x >> 3;
    const int id = ((int)blockIdx.x & 7) * chunk + ((int)blockIdx.x >> 3);
    int tileid = id, ksplit = 0;
    if constexpr (KSPLITS == 2) { ksplit = id & 1; tileid = id >> 1; }
    const int kof = ksplit * Keff;
    const size_t row0 = (size_t)(tileid / nbx) * 256;
    const int col0 = (tileid % nbx) * 256;
    const int srow = lane >> 3;
    const int sgr = (lane & 7) ^ srow;
    const int NT = Keff >> 6;
    f32x4 acc[8][4] = {};

    auto stage_half = [&](int isB, int buf, int t, int h) {
        const u16* g = isB ? Bt : A;
        const size_t grow0 = isB ? (size_t)col0 : row0;
        char* base = isB ? (char*)&Bs[buf][0] : (char*)&As[buf][0];
#pragma unroll
        for (int l = 0; l < 2; l++) {
            int rt = h * 128 + l * 64 + wave * 8;
            gload16(base + rt * 128,
                    (const char*)(g + (grow0 + rt + srow) * lda + kof + t * 64 + sgr * 8));
        }
    };
    auto rdA = [&](int cur, int mh, int m, int kk) -> bf16x8 {
        int r = wm * 128 + mh * 64 + m * 16 + lr;
        int gi = kk * 4 + lg;
        return *(const bf16x8*)((char*)&As[cur][0] + r * 128 + ((gi ^ (r & 7)) << 4));
    };
    auto rdB = [&](int cur, int nh, int n, int kk) -> bf16x8 {
        int r = wn * 64 + nh * 32 + n * 16 + lr;
        int gi = kk * 4 + lg;
        return *(const bf16x8*)((char*)&Bs[cur][0] + r * 128 + ((gi ^ (r & 7)) << 4));
    };

    stage_half(0, 0, 0, 0); stage_half(0, 0, 0, 1);
    stage_half(1, 0, 0, 0); stage_half(1, 0, 0, 1);
    stage_half(1, 1, 1, 0); stage_half(1, 1, 1, 1);
    asm volatile("s_waitcnt vmcnt(4)" ::: "memory");
    __builtin_amdgcn_s_barrier();

    bf16x8 aF[4][2], b0F[2][2], b1F[2][2];
    for (int t = 0; t < NT; ++t) {
        const int cur = t & 1, nxt = cur ^ 1;
        // ---- P0 ----
#pragma unroll
        for (int m = 0; m < 4; m++) { aF[m][0] = rdA(cur, 0, m, 0); aF[m][1] = rdA(cur, 0, m, 1); }
#pragma unroll
        for (int n = 0; n < 2; n++) { b0F[n][0] = rdB(cur, 0, n, 0); b0F[n][1] = rdB(cur, 0, n, 1); }
        if (t + 1 < NT) stage_half(0, nxt, t + 1, 0);
        __builtin_amdgcn_s_barrier();
        asm volatile("s_waitcnt lgkmcnt(0)" ::: "memory");
        __builtin_amdgcn_sched_barrier(0);
        __builtin_amdgcn_s_setprio(1);
#pragma unroll
        for (int m = 0; m < 4; m++)
#pragma unroll
            for (int n = 0; n < 2; n++) {
                acc[m][n] = MFMA(aF[m][0], b0F[n][0], acc[m][n]);
                acc[m][n] = MFMA(aF[m][1], b0F[n][1], acc[m][n]);
            }
        __builtin_amdgcn_s_setprio(0);
        __builtin_amdgcn_s_barrier();
        // ---- P1 ----
#pragma unroll
        for (int n = 0; n < 2; n++) { b1F[n][0] = rdB(cur, 1, n, 0); b1F[n][1] = rdB(cur, 1, n, 1); }
        if (t + 1 < NT) stage_half(0, nxt, t + 1, 1);
        __builtin_amdgcn_s_barrier();
        asm volatile("s_waitcnt lgkmcnt(0)" ::: "memory");
        __builtin_amdgcn_sched_barrier(0);
        __builtin_amdgcn_s_setprio(1);
#pragma unroll
        for (int m = 0; m < 4; m++)
#pragma unroll
            for (int n = 0; n < 2; n++) {
                acc[m][2 + n] = MFMA(aF[m][0], b1F[n][0], acc[m][2 + n]);
                acc[m][2 + n] = MFMA(aF[m][1], b1F[n][1], acc[m][2 + n]);
            }
        __builtin_amdgcn_s_setprio(0);
        __builtin_amdgcn_s_barrier();
        // ---- P2 ----
#pragma unroll
        for (int m = 0; m < 4; m++) { aF[m][0] = rdA(cur, 1, m, 0); aF[m][1] = rdA(cur, 1, m, 1); }
        if (t + 2 < NT) stage_half(1, cur, t + 2, 0);
        __builtin_amdgcn_s_barrier();
        asm volatile("s_waitcnt lgkmcnt(0)" ::: "memory");
        __builtin_amdgcn_sched_barrier(0);
        __builtin_amdgcn_s_setprio(1);
#pragma unroll
        for (int m = 0; m < 4; m++)
#pragma unroll
            for (int n = 0; n < 2; n++) {
                acc[4 + m][2 + n] = MFMA(aF[m][0], b1F[n][0], acc[4 + m][2 + n]);
                acc[4 + m][2 + n] = MFMA(aF[m][1], b1F[n][1], acc[4 + m][2 + n]);
            }
        __builtin_amdgcn_s_setprio(0);
        __builtin_amdgcn_s_barrier();
        // ---- P3 ----
        if (t + 2 < NT) stage_half(1, cur, t + 2, 1);
        if (t + 1 < NT) {
            if (t + 2 < NT) asm volatile("s_waitcnt vmcnt(4)" ::: "memory");
            else            asm volatile("s_waitcnt vmcnt(0)" ::: "memory");
        }
        __builtin_amdgcn_s_barrier();
        __builtin_amdgcn_s_setprio(1);
#pragma unroll
        for (int m = 0; m < 4; m++)
#pragma unroll
            for (int n = 0; n < 2; n++) {
                acc[4 + m][n] = MFMA(aF[m][0], b0F[n][0], acc[4 + m][n]);
                acc[4 + m][n] = MFMA(aF[m][1], b0F[n][1], acc[4 + m][n]);
            }
        __builtin_amdgcn_s_setprio(0);
        __builtin_amdgcn_s_barrier();
    }
    u16* Cout = (KSPLITS == 2 && ksplit) ? Cb2 : Cb;
#pragma unroll
    for (int m = 0; m < 8; m++)
#pragma unroll
        for (int n = 0; n < 4; n++)
#pragma unroll
            for (int i = 0; i < 4; i++) {
                int rg = (int)row0 + wm * 128 + m * 16 + lg * 4 + i;
                int cg = col0 + wn * 64 + n * 16 + lr;
                float v = acc[m][n][i];
                if constexpr (EPI == 2) {
                    v += bias[cg];
                    v = v > 0.f ? v : 0.f;
                    Cout[(size_t)rg * N + cg] = f2bf(v);
                } else {
                    Cout[(size_t)rg * N + cg] = f2bf(v);
                }
            }
}

// ------- flash attention: 8-wave QBLK=256, 32x32 MFMA, in-reg P, amask -------
__global__ __launch_bounds__(512) void k_attn(const u16* __restrict__ qkv,
                                              const u16* __restrict__ vT,
                                              const u32* __restrict__ mbits,
                                              const u32* __restrict__ amask,
                                              u16* __restrict__ outb) {
    __shared__ u16 Kt[2][64 * 64];
    __shared__ u16 Vt[2][64 * 64];
    const int tid = threadIdx.x, lane = tid & 63, wave = tid >> 6;
    const int l31 = lane & 31, hi = lane >> 5;
    const int id0 = blockIdx.y * 8 + blockIdx.x;
    const int id = (id0 & 7) * 64 + (id0 >> 3);
    const int bh = id >> 3;
    const int b = bh >> 4, h = bh & 15;
    const int qb0 = (id & 7) * 256;
    const size_t qbase = (size_t)bh * (2048 * 64);
    const size_t kbase = (size_t)(64 + bh) * (2048 * 64);
    const size_t vtbase = (size_t)bh * (64 * 2048);

    bf16x8 qf[4];
    const int q0 = qb0 + wave * 32;
#pragma unroll
    for (int dstep = 0; dstep < 4; dstep++)
        qf[dstep] = *(const bf16x8*)(qkv + qbase + (size_t)(q0 + l31) * 64 +
                                     dstep * 16 + hi * 8);

    u16x8 ones_u;
#pragma unroll
    for (int e = 0; e < 8; e++) ones_u[e] = 0x3f80;
    const bf16x8 ones8 = *(const bf16x8*)&ones_u;

    f32x16 o0 = {}, o1 = {}, lacc = {};
    f32x16 zin;
#pragma unroll
    for (int r = 0; r < 16; r++) zin[r] = -16.f;

    const int srow = tid >> 3, sg8 = tid & 7;
    const int swzs = (srow & 7) << 4;
    const int sb0 = srow * 128 + sg8 * 16;

    u16x8 krA, vrA;
    auto issue_loads = [&](int kv0n) {
        krA = *(const u16x8*)(qkv + kbase + (size_t)(kv0n + srow) * 64 + sg8 * 8);
        vrA = *(const u16x8*)(vT + vtbase + (size_t)srow * 2048 + kv0n + sg8 * 8);
    };
    auto write_tile = [&](int buf) {
        *(u16x8*)((char*)&Kt[buf][0] + (sb0 ^ swzs)) = krA;
        *(u16x8*)((char*)&Vt[buf][0] + (sb0 ^ swzs)) = vrA;
    };

    const u32 am = amask[b * 2048 + qb0 + wave * 32 + l31];
    const int rK0 = l31, rK1 = 32 + l31;
    const int swK0 = (rK0 & 7) << 4, swK1 = (rK1 & 7) << 4;

    issue_loads(0);
    write_tile(0);
    for (int t = 0; t < 32; ++t) {
        const int cur = t & 1;
        if (t + 1 < 32) issue_loads((t + 1) * 64);
        asm volatile("s_waitcnt lgkmcnt(0)" ::: "memory");
        __builtin_amdgcn_s_barrier();

        f32x16 st0 = zin, st1 = zin;
        __builtin_amdgcn_s_setprio(1);
#pragma unroll
        for (int dstep = 0; dstep < 4; dstep++) {
            bf16x8 kf0 = *(const bf16x8*)((char*)&Kt[cur][0] + rK0 * 128 +
                                          ((dstep * 32 + hi * 16) ^ swK0));
            bf16x8 kf1 = *(const bf16x8*)((char*)&Kt[cur][0] + rK1 * 128 +
                                          ((dstep * 32 + hi * 16) ^ swK1));
            st0 = MFMA32(kf0, qf[dstep], st0);
            st1 = MFMA32(kf1, qf[dstep], st1);
        }
        __builtin_amdgcn_s_setprio(0);

        if (!((am >> t) & 1u)) {  // cold path: exact per-element mask
            uint2 mw = *(const uint2*)&mbits[(size_t)(b * 2048 + qb0 + wave * 32 + l31) * 64 + 2 * t];
            u32 mw0 = mw.x >> (hi * 4), mw1 = mw.y >> (hi * 4);
#pragma unroll
            for (int r = 0; r < 16; r++) {
                int sh = (r & 3) + 8 * (r >> 2);
                if (!((mw0 >> sh) & 1u)) st0[r] = -1e9f;
                if (!((mw1 >> sh) & 1u)) st1[r] = -1e9f;
            }
        }
        bf16x8 pa[4];
#pragma unroll
        for (int r = 0; r < 16; r++) { st0[r] = v_exp2(st0[r]); st1[r] = v_exp2(st1[r]); }
#pragma unroll
        for (int kvb = 0; kvb < 2; kvb++) {
            const f32x16& st = kvb ? st1 : st0;
            u32 wA[4], wB[4];
#pragma unroll
            for (int g = 0; g < 4; g++) {
                wA[g] = cvt_pk_bf16(st[4 * g], st[4 * g + 1]);
                wB[g] = cvt_pk_bf16(st[4 * g + 2], st[4 * g + 3]);
            }
#pragma unroll
            for (int s = 0; s < 2; s++) {
                u32 xA = wA[2 * s], yA = wA[2 * s + 1];
                asm("v_permlane32_swap_b32 %0, %1" : "+v"(xA), "+v"(yA));
                u32 xB = wB[2 * s], yB = wB[2 * s + 1];
                asm("v_permlane32_swap_b32 %0, %1" : "+v"(xB), "+v"(yB));
                union { u32 w[4]; bf16x8 v; } pk;
                pk.w[0] = xA; pk.w[1] = xB; pk.w[2] = yA; pk.w[3] = yB;
                pa[kvb * 2 + s] = pk.v;
            }
        }
        __builtin_amdgcn_s_setprio(1);
#pragma unroll
        for (int ks = 0; ks < 4; ks++) {
            bf16x8 vb0 = *(const bf16x8*)((char*)&Vt[cur][0] + rK0 * 128 +
                                          ((ks * 32 + hi * 16) ^ swK0));
            bf16x8 vb1 = *(const bf16x8*)((char*)&Vt[cur][0] + rK1 * 128 +
                                          ((ks * 32 + hi * 16) ^ swK1));
            lacc = MFMA32(pa[ks], ones8, lacc);
            o0 = MFMA32(pa[ks], vb0, o0);
            o1 = MFMA32(pa[ks], vb1, o1);
        }
        __builtin_amdgcn_s_setprio(0);
        if (t + 1 < 32) write_tile(cur ^ 1);
    }
#pragma unroll
    for (int r = 0; r < 16; r++) {
        float inv = 1.f / lacc[r];
        int qg = qb0 + wave * 32 + (r & 3) + 8 * (r >> 2) + 4 * hi;
        size_t rowb = (size_t)(b * 2048 + qg) * 1024 + h * 64 + l31;
        outb[rowb] = f2bf(o0[r] * inv);
        outb[rowb + 32] = f2bf(o1[r] * inv);
    }
}

// ------- LayerNorm over bf16 input (residual pre-added), bf16 out -------
__global__ __launch_bounds__(256) void k_ln_b(const u16* __restrict__ tin,
                                              u16* __restrict__ outb,
                                              const float* __restrict__ alpha,
                                              const float* __restrict__ beta) {
    const int row = blockIdx.x, tid = threadIdx.x;
    const u16x4 tv = ((const u16x4*)(tin + (size_t)row * 1024))[tid];
    f32x4 t;
#pragma unroll
    for (int i = 0; i < 4; i++) t[i] = bf2f(tv[i]);
    float s = t[0] + t[1] + t[2] + t[3];
    float ss = t[0] * t[0] + t[1] * t[1] + t[2] * t[2] + t[3] * t[3];
#pragma unroll
    for (int m2 = 1; m2 < 64; m2 <<= 1) {
        s += __shfl_xor(s, m2);
        ss += __shfl_xor(ss, m2);
    }
    __shared__ float ps[4], pss[4];
    if ((tid & 63) == 0) { ps[tid >> 6] = s; pss[tid >> 6] = ss; }
    __syncthreads();
    s = ps[0] + ps[1] + ps[2] + ps[3];
    ss = pss[0] + pss[1] + pss[2] + pss[3];
    const float mean = s * (1.f / 1024.f);
    float var = (ss - 1024.f * mean * mean) * (1.f / 1023.f);
    var = fmaxf(var, 0.f);
    const float inv = alpha[0] / (sqrtf(var) + 1e-6f);
    const float bet = beta[0];
    u16x4 ob;
#pragma unroll
    for (int i = 0; i < 4; i++) ob[i] = f2bf((t[i] - mean) * inv + bet);
    ((u16x4*)(outb + (size_t)row * 1024))[tid] = ob;
}

// ------- LN over sum of two bf16 split-K partials + bias + bf16 residual -------
__global__ __launch_bounds__(256) void k_ln_sum2(const u16* __restrict__ p0,
                                                 const u16* __restrict__ p1,
                                                 const u16* __restrict__ residb,
                                                 const float* __restrict__ bias,
                                                 float* __restrict__ outf,
                                                 const float* __restrict__ alpha,
                                                 const float* __restrict__ beta) {
    const int row = blockIdx.x, tid = threadIdx.x;
    const u16x4 av = ((const u16x4*)(p0 + (size_t)row * 1024))[tid];
    const u16x4 cv = ((const u16x4*)(p1 + (size_t)row * 1024))[tid];
    const u16x4 rv = ((const u16x4*)(residb + (size_t)row * 1024))[tid];
    const f32x4 bb = ((const f32x4*)bias)[tid];
    f32x4 t;
#pragma unroll
    for (int i = 0; i < 4; i++) t[i] = bf2f(av[i]) + bf2f(cv[i]) + bf2f(rv[i]) + bb[i];
    float s = t[0] + t[1] + t[2] + t[3];
    float ss = t[0] * t[0] + t[1] * t[1] + t[2] * t[2] + t[3] * t[3];
#pragma unroll
    for (int m2 = 1; m2 < 64; m2 <<= 1) {
        s += __shfl_xor(s, m2);
        ss += __shfl_xor(ss, m2);
    }
    __shared__ float ps[4], pss[4];
    if ((tid & 63) == 0) { ps[tid >> 6] = s; pss[tid >> 6] = ss; }
    __syncthreads();
    s = ps[0] + ps[1] + ps[2] + ps[3];
    ss = pss[0] + pss[1] + pss[2] + pss[3];
    const float mean = s * (1.f / 1024.f);
    float var = (ss - 1024.f * mean * mean) * (1.f / 1023.f);
    var = fmaxf(var, 0.f);
    const float inv = alpha[0] / (sqrtf(var) + 1e-6f);
    const float bet = beta[0];
    f32x4 oo;
#pragma unroll
    for (int i = 0; i < 4; i++) oo[i] = (t[i] - mean) * inv + bet;
    ((f32x4*)(outf + (size_t)row * 1024))[tid] = oo;
}

// ---------------- launch ----------------
extern "C" void kernel_launch(void* const* d_in, const int* in_sizes, int n_in,
                              void* d_out, int out_size, void* d_ws, size_t ws_size,
                              hipStream_t stream) {
    const float* x   = (const float*)d_in[0];
    const int*   msk = (const int*)d_in[1];
    const float* wq  = (const float*)d_in[2];
    const float* wk  = (const float*)d_in[3];
    const float* wv  = (const float*)d_in[4];
    const float* wo  = (const float*)d_in[5];
    const float* w1  = (const float*)d_in[6];
    const float* b1  = (const float*)d_in[7];
    const float* w2  = (const float*)d_in[8];
    const float* b2  = (const float*)d_in[9];
    const float* a1  = (const float*)d_in[10];
    const float* bt1 = (const float*)d_in[11];
    const float* a2  = (const float*)d_in[12];
    const float* bt2 = (const float*)d_in[13];
    float* out = (float*)d_out;

    char* ws = (char*)d_ws;
    size_t off = 0;
    auto alloc = [&](size_t bytes) {
        void* p = ws + off;
        off += (bytes + 255) & ~(size_t)255;
        return p;
    };
    u16* xb    = (u16*)alloc((size_t)M_ * D_ * 2);
    u16* wqkvT = (u16*)alloc((size_t)3 * D_ * D_ * 2);  // contiguous with woT
    u16* woT   = (u16*)alloc((size_t)D_ * D_ * 2);
    u16* w1T   = (u16*)alloc((size_t)DFF_ * D_ * 2);
    u16* w2T   = (u16*)alloc((size_t)D_ * DFF_ * 2);
    u32* mbits = (u32*)alloc((size_t)B_ * S_ * 64 * 4);
    u32* amsk  = (u32*)alloc((size_t)B_ * S_ * 4);
    u16* aout  = (u16*)alloc((size_t)M_ * D_ * 2);
    u16* yb    = (u16*)alloc((size_t)M_ * D_ * 2);     // WO out + resid, bf16
    u16* y0b   = (u16*)alloc((size_t)M_ * D_ * 2);     // FFN2 partial 0, bf16
    u16* y1b   = (u16*)alloc((size_t)M_ * D_ * 2);     // FFN2 partial 1, bf16
    u16* x1b   = (u16*)alloc((size_t)M_ * D_ * 2);     // LN1 out, bf16
    u16* vTb   = (u16*)alloc((size_t)64 * 64 * 2048 * 2);
    u16* qkv   = (u16*)alloc((size_t)M_ * DFF_ * 2);
    u16* hft   = qkv;

    // 1) pre-pass
    k_pack_amask<<<dim3((B_ * S_) / 4), 256, 0, stream>>>(msk, mbits, amsk);
    k_cast_bf16<<<dim3((M_ * D_ / 4) / 256), 256, 0, stream>>>(x, xb, M_ * D_ / 4);
    dim3 tb(32, 8);
    k_transpose_cast4<<<dim3(32, 32, 4), tb, 0, stream>>>(wq, wk, wv, wo, wqkvT);
    k_transpose_cast<<<dim3(128, 32), tb, 0, stream>>>(w1, w1T, D_, DFF_);
    k_transpose_cast<<<dim3(32, 128), tb, 0, stream>>>(w2, w2T, DFF_, D_);

    // 2) QKV projection (128^2, 1536 blocks); coalesced LDS epilogue; V -> vTb.
    k_gemm8<0><<<dim3(1536), 512, 0, stream>>>(xb, wqkvT, qkv, nullptr,
                                               nullptr, vTb, 3 * D_, D_);
    // 3) flash attention (8-wave, QBLK=256, 512 blocks)
    k_attn<<<dim3(8, 64), 512, 0, stream>>>(qkv, vTb, mbits, amsk, aout);
    // 4) output projection + bf16 residual -> yb (bf16)
    k_gemm8<1><<<dim3(512), 512, 0, stream>>>(aout, woT, yb, nullptr, xb,
                                              nullptr, D_, D_);
    // 5) LN1 (bf16 in/out)
    k_ln_b<<<dim3(M_), 256, 0, stream>>>(yb, x1b, a1, bt1);
    // 6) FFN1 (256^2 4-phase, 512 blocks)
    k_gemm256<2, 1><<<dim3(512), 512, 0, stream>>>(x1b, w1T, hft, nullptr,
                                                   b1, DFF_, D_, D_);
    // 7) FFN2 split-K=2 (256 blocks): bf16 partials y0b, y1b
    k_gemm256<3, 2><<<dim3(256), 512, 0, stream>>>(hft, w2T, y0b, y1b,
                                                   nullptr, D_, DFF_ / 2, DFF_);
    // 8) LN2 over (y0b + y1b + b2 + x1b) -> d_out
    k_ln_sum2<<<dim3(M_), 256, 0, stream>>>(y0b, y1b, x1b, b2, out, a2, bt2);
}

// Round 15
// 371.681 us; speedup vs baseline: 1.0184x; 1.0184x over previous
//
#include <hip/hip_runtime.h>
#include <stdint.h>

typedef __bf16 bf16x8 __attribute__((ext_vector_type(8)));
typedef float f32x4 __attribute__((ext_vector_type(4)));
typedef float f32x16 __attribute__((ext_vector_type(16)));
typedef unsigned short u16;
typedef u16 u16x8 __attribute__((ext_vector_type(8)));
typedef u16 u16x4 __attribute__((ext_vector_type(4)));
typedef uint32_t u32;

#define DEV __device__ __forceinline__
#define MFMA(a, b, c) __builtin_amdgcn_mfma_f32_16x16x32_bf16(a, b, c, 0, 0, 0)
#define MFMA32(a, b, c) __builtin_amdgcn_mfma_f32_32x32x16_bf16(a, b, c, 0, 0, 0)

static constexpr int B_ = 4, S_ = 2048, M_ = 8192, D_ = 1024, H_ = 16, DFF_ = 4096;

DEV u16 f2bf(float f) {
    union { float f; u32 u; } c; c.f = f;
    u32 u = c.u;
    return (u16)((u + 0x7fffu + ((u >> 16) & 1u)) >> 16);
}

DEV float bf2f(u16 v) {
    union { u32 u; float f; } c; c.u = (u32)v << 16;
    return c.f;
}

DEV u32 cvt_pk_bf16(float lo, float hi) {
    u32 r;
    asm("v_cvt_pk_bf16_f32 %0, %1, %2" : "=v"(r) : "v"(lo), "v"(hi));
    return r;
}

DEV float v_exp2(float x) {  // raw 2^x
    float r;
    asm("v_exp_f32 %0, %1" : "=v"(r) : "v"(x));
    return r;
}

DEV void gload16(void* lds, const void* g) {
    __builtin_amdgcn_global_load_lds(
        (const __attribute__((address_space(1))) unsigned int*)g,
        (__attribute__((address_space(3))) unsigned int*)lds, 16, 0, 0);
}

// ---------------- pre-pass kernels ----------------

// fused: pack mask bits + per-row tile-allones bitmap (wave per row)
__global__ __launch_bounds__(256) void k_pack_amask(const int* __restrict__ m,
                                                    u32* __restrict__ bits,
                                                    u32* __restrict__ am) {
    const int lane = threadIdx.x & 63, wv = threadIdx.x >> 6;
    const int row = blockIdx.x * 4 + wv;
    const int4* s = (const int4*)(m + ((size_t)row * 64 + lane) * 32);
    u32 r = 0;
#pragma unroll
    for (int j = 0; j < 8; j++) {
        int4 v = s[j];
        r |= (u32)(v.x != 0) << (j * 4) | (u32)(v.y != 0) << (j * 4 + 1) |
             (u32)(v.z != 0) << (j * 4 + 2) | (u32)(v.w != 0) << (j * 4 + 3);
    }
    bits[(size_t)row * 64 + lane] = r;
    unsigned long long b = __ballot(r == 0xffffffffu);
    if (lane == 0) {
        u32 a = 0;
#pragma unroll
        for (int t = 0; t < 32; t++)
            a |= (u32)(((b >> (2 * t)) & 3ull) == 3ull) << t;
        am[row] = a;
    }
}

__global__ __launch_bounds__(256) void k_cast_bf16(const float* __restrict__ s,
                                                   u16* __restrict__ d, int n4) {
    int i = blockIdx.x * 256 + threadIdx.x;
    if (i >= n4) return;
    f32x4 v = ((const f32x4*)s)[i];
    u16x4 o;
    o[0] = f2bf(v[0]); o[1] = f2bf(v[1]); o[2] = f2bf(v[2]); o[3] = f2bf(v[3]);
    ((u16x4*)d)[i] = o;
}

// src [K][N] f32 -> dst [N][K] bf16
__global__ void k_transpose_cast(const float* __restrict__ s, u16* __restrict__ d,
                                 int K, int N) {
    __shared__ float t[32][33];
    int n0 = blockIdx.x * 32, k0 = blockIdx.y * 32;
    int tx = threadIdx.x, ty = threadIdx.y;
#pragma unroll
    for (int i = 0; i < 4; i++)
        t[ty + i * 8][tx] = s[(size_t)(k0 + ty + i * 8) * N + n0 + tx];
    __syncthreads();
#pragma unroll
    for (int i = 0; i < 4; i++)
        d[(size_t)(n0 + ty + i * 8) * K + k0 + tx] = f2bf(t[tx][ty + i * 8]);
}

// four DxD transposes in one launch
__global__ void k_transpose_cast4(const float* __restrict__ s0,
                                  const float* __restrict__ s1,
                                  const float* __restrict__ s2,
                                  const float* __restrict__ s3,
                                  u16* __restrict__ dbase) {
    __shared__ float t[32][33];
    const int z = blockIdx.z;
    const float* s = (z == 0) ? s0 : (z == 1) ? s1 : (z == 2) ? s2 : s3;
    u16* d = dbase + (size_t)z * D_ * D_;
    int n0 = blockIdx.x * 32, k0 = blockIdx.y * 32;
    int tx = threadIdx.x, ty = threadIdx.y;
#pragma unroll
    for (int i = 0; i < 4; i++)
        t[ty + i * 8][tx] = s[(size_t)(k0 + ty + i * 8) * D_ + n0 + tx];
    __syncthreads();
#pragma unroll
    for (int i = 0; i < 4; i++)
        d[(size_t)(n0 + ty + i * 8) * D_ + k0 + tx] = f2bf(t[tx][ty + i * 8]);
}

// ---- 128x128 8-wave GEMM, BK=64, dbuf LDS, counted vmcnt, T2 swizzle ----
// EPI 0: QKV scatter (Q scaled by 0.125*log2e; V written transposed to Vt)
// EPI 1: +bf16 resid, bf16 out; EPI 2: +bias relu bf16
template <int EPI>
__global__ __launch_bounds__(512, 4) void k_gemm8(const u16* __restrict__ A,
                                                  const u16* __restrict__ Bt,
                                                  u16* __restrict__ Cb,
                                                  const float* __restrict__ bias,
                                                  const u16* __restrict__ residb,
                                                  u16* __restrict__ Vt,
                                                  int N, int K) {
    __shared__ u16 As[2][128 * 64];
    __shared__ u16 Bs[2][128 * 64];
    const int tid = threadIdx.x, lane = tid & 63, wave = tid >> 6;
    const int lr = lane & 15, lg = lane >> 4;
    const int wm = wave >> 1, wn = wave & 1;
    const int nbx = N >> 7;
    const int chunk = gridDim.x >> 3;
    const int id = ((int)blockIdx.x & 7) * chunk + ((int)blockIdx.x >> 3);
    const size_t row0 = (size_t)(id / nbx) * 128;
    const int col0 = (id % nbx) * 128;
    const int srow = lane >> 3;
    const int sgr = (lane & 7) ^ srow;
    const int NT = K >> 6;
    f32x4 acc[2][4] = {};

    auto stage = [&](int buf, int t) {
#pragma unroll
        for (int i = 0; i < 2; i++) {
            int c = i * 8 + wave;
            gload16((char*)&As[buf][0] + c * 1024,
                    (const char*)(A + (row0 + c * 8 + srow) * K + t * 64 + sgr * 8));
        }
#pragma unroll
        for (int i = 0; i < 2; i++) {
            int c = i * 8 + wave;
            gload16((char*)&Bs[buf][0] + c * 1024,
                    (const char*)(Bt + (size_t)(col0 + c * 8 + srow) * K + t * 64 + sgr * 8));
        }
    };

    stage(0, 0);
    for (int t = 0; t < NT; ++t) {
        const int cur = t & 1;
        if (t + 1 < NT) {
            stage(cur ^ 1, t + 1);
            asm volatile("s_waitcnt vmcnt(4)" ::: "memory");
        } else {
            asm volatile("s_waitcnt vmcnt(0)" ::: "memory");
        }
        __builtin_amdgcn_s_barrier();
        asm volatile("" ::: "memory");
        bf16x8 bF[4][2];
#pragma unroll
        for (int n = 0; n < 4; n++) {
            int r = wn * 64 + n * 16 + lr;
            int rb = r * 128, sw = (r & 7) << 4;
#pragma unroll
            for (int ks = 0; ks < 2; ks++)
                bF[n][ks] = *(const bf16x8*)((char*)&Bs[cur][0] +
                                             (rb + ((ks * 64 + lg * 16) ^ sw)));
        }
#pragma unroll
        for (int m = 0; m < 2; m++) {
            int r = wm * 32 + m * 16 + lr;
            int rb = r * 128, sw = (r & 7) << 4;
            bf16x8 a0 = *(const bf16x8*)((char*)&As[cur][0] + (rb + ((lg * 16) ^ sw)));
            bf16x8 a1 = *(const bf16x8*)((char*)&As[cur][0] + (rb + ((64 + lg * 16) ^ sw)));
            __builtin_amdgcn_s_setprio(1);
#pragma unroll
            for (int n = 0; n < 4; n++) {
                acc[m][n] = MFMA(a0, bF[n][0], acc[m][n]);
                acc[m][n] = MFMA(a1, bF[n][1], acc[m][n]);
            }
            __builtin_amdgcn_s_setprio(0);
        }
        asm volatile("" ::: "memory");
        __builtin_amdgcn_s_barrier();
    }
#pragma unroll
    for (int m = 0; m < 2; m++)
#pragma unroll
        for (int n = 0; n < 4; n++) {
            const int cg = col0 + wn * 64 + n * 16 + lr;
            const int rbase = (int)row0 + wm * 32 + m * 16 + lg * 4;
            if constexpr (EPI == 0) {
                const int proj = cg >> 10, hh = (cg >> 6) & 15, dk = cg & 63;
                const int b = rbase >> 11, s = rbase & 2047;
                if (proj == 2) {  // V: write transposed, vT[b*16+hh][dk][s..s+3]
                    u16x4 ov;
#pragma unroll
                    for (int i = 0; i < 4; i++) ov[i] = f2bf(acc[m][n][i]);
                    *(u16x4*)(Vt + ((size_t)(b * 16 + hh) * 64 + dk) * 2048 + s) = ov;
                } else {
                    const float sc = (proj == 0) ? 0.1803368801111832f : 1.f;
                    size_t base = ((size_t)(proj * 64 + b * 16 + hh) * 2048 + s) * 64 + dk;
#pragma unroll
                    for (int i = 0; i < 4; i++)
                        Cb[base + (size_t)i * 64] = f2bf(acc[m][n][i] * sc);
                }
            } else {
#pragma unroll
                for (int i = 0; i < 4; i++) {
                    const int rg = rbase + i;
                    float v = acc[m][n][i];
                    if constexpr (EPI == 1) {
                        Cb[(size_t)rg * N + cg] =
                            f2bf(v + bf2f(residb[(size_t)rg * N + cg]));
                    } else {
                        v += bias[cg];
                        v = v > 0.f ? v : 0.f;
                        Cb[(size_t)rg * N + cg] = f2bf(v);
                    }
                }
            }
        }
}

// ---- 256x256 8-wave 4-phase GEMM, BK=64, dbuf LDS, counted vmcnt ----
// EPI 2: +bias relu bf16 ; EPI 3: bf16 split-K partial store
template <int EPI, int KSPLITS>
__global__ __launch_bounds__(512, 2) void k_gemm256(const u16* __restrict__ A,
                                                    const u16* __restrict__ Bt,
                                                    u16* __restrict__ Cb,
                                                    u16* __restrict__ Cb2,
                                                    const float* __restrict__ bias,
                                                    int N, int Keff, int lda) {
    __shared__ u16 As[2][256 * 64];
    __shared__ u16 Bs[2][256 * 64];
    const int tid = threadIdx.x, lane = tid & 63, wave = tid >> 6;
    const int lr = lane & 15, lg = lane >> 4;
    const int wm = wave >> 2, wn = wave & 3;
    const int nbx = N >> 8;
    const int chunk = gridDim.x >> 3;
    const int id = ((int)blockIdx.x & 7) * chunk + ((int)blockIdx.x >> 3);
    int tileid = id, ksplit = 0;
    if constexpr (KSPLITS == 2) { ksplit = id & 1; tileid = id >> 1; }
    const int kof = ksplit * Keff;
    const size_t row0 = (size_t)(tileid / nbx) * 256;
    const int col0 = (tileid % nbx) * 256;
    const int srow = lane >> 3;
    const int sgr = (lane & 7) ^ srow;
    const int NT = Keff >> 6;
    f32x4 acc[8][4] = {};

    auto stage_half = [&](int isB, int buf, int t, int h) {
        const u16* g = isB ? Bt : A;
        const size_t grow0 = isB ? (size_t)col0 : row0;
        char* base = isB ? (char*)&Bs[buf][0] : (char*)&As[buf][0];
#pragma unroll
        for (int l = 0; l < 2; l++) {
            int rt = h * 128 + l * 64 + wave * 8;
            gload16(base + rt * 128,
                    (const char*)(g + (grow0 + rt + srow) * lda + kof + t * 64 + sgr * 8));
        }
    };
    auto rdA = [&](int cur, int mh, int m, int kk) -> bf16x8 {
        int r = wm * 128 + mh * 64 + m * 16 + lr;
        int gi = kk * 4 + lg;
        return *(const bf16x8*)((char*)&As[cur][0] + r * 128 + ((gi ^ (r & 7)) << 4));
    };
    auto rdB = [&](int cur, int nh, int n, int kk) -> bf16x8 {
        int r = wn * 64 + nh * 32 + n * 16 + lr;
        int gi = kk * 4 + lg;
        return *(const bf16x8*)((char*)&Bs[cur][0] + r * 128 + ((gi ^ (r & 7)) << 4));
    };

    stage_half(0, 0, 0, 0); stage_half(0, 0, 0, 1);
    stage_half(1, 0, 0, 0); stage_half(1, 0, 0, 1);
    stage_half(1, 1, 1, 0); stage_half(1, 1, 1, 1);
    asm volatile("s_waitcnt vmcnt(4)" ::: "memory");
    __builtin_amdgcn_s_barrier();

    bf16x8 aF[4][2], b0F[2][2], b1F[2][2];
    for (int t = 0; t < NT; ++t) {
        const int cur = t & 1, nxt = cur ^ 1;
        // ---- P0 ----
#pragma unroll
        for (int m = 0; m < 4; m++) { aF[m][0] = rdA(cur, 0, m, 0); aF[m][1] = rdA(cur, 0, m, 1); }
#pragma unroll
        for (int n = 0; n < 2; n++) { b0F[n][0] = rdB(cur, 0, n, 0); b0F[n][1] = rdB(cur, 0, n, 1); }
        if (t + 1 < NT) stage_half(0, nxt, t + 1, 0);
        __builtin_amdgcn_s_barrier();
        asm volatile("s_waitcnt lgkmcnt(0)" ::: "memory");
        __builtin_amdgcn_sched_barrier(0);
        __builtin_amdgcn_s_setprio(1);
#pragma unroll
        for (int m = 0; m < 4; m++)
#pragma unroll
            for (int n = 0; n < 2; n++) {
                acc[m][n] = MFMA(aF[m][0], b0F[n][0], acc[m][n]);
                acc[m][n] = MFMA(aF[m][1], b0F[n][1], acc[m][n]);
            }
        __builtin_amdgcn_s_setprio(0);
        __builtin_amdgcn_s_barrier();
        // ---- P1 ----
#pragma unroll
        for (int n = 0; n < 2; n++) { b1F[n][0] = rdB(cur, 1, n, 0); b1F[n][1] = rdB(cur, 1, n, 1); }
        if (t + 1 < NT) stage_half(0, nxt, t + 1, 1);
        __builtin_amdgcn_s_barrier();
        asm volatile("s_waitcnt lgkmcnt(0)" ::: "memory");
        __builtin_amdgcn_sched_barrier(0);
        __builtin_amdgcn_s_setprio(1);
#pragma unroll
        for (int m = 0; m < 4; m++)
#pragma unroll
            for (int n = 0; n < 2; n++) {
                acc[m][2 + n] = MFMA(aF[m][0], b1F[n][0], acc[m][2 + n]);
                acc[m][2 + n] = MFMA(aF[m][1], b1F[n][1], acc[m][2 + n]);
            }
        __builtin_amdgcn_s_setprio(0);
        __builtin_amdgcn_s_barrier();
        // ---- P2 ----
#pragma unroll
        for (int m = 0; m < 4; m++) { aF[m][0] = rdA(cur, 1, m, 0); aF[m][1] = rdA(cur, 1, m, 1); }
        if (t + 2 < NT) stage_half(1, cur, t + 2, 0);
        __builtin_amdgcn_s_barrier();
        asm volatile("s_waitcnt lgkmcnt(0)" ::: "memory");
        __builtin_amdgcn_sched_barrier(0);
        __builtin_amdgcn_s_setprio(1);
#pragma unroll
        for (int m = 0; m < 4; m++)
#pragma unroll
            for (int n = 0; n < 2; n++) {
                acc[4 + m][2 + n] = MFMA(aF[m][0], b1F[n][0], acc[4 + m][2 + n]);
                acc[4 + m][2 + n] = MFMA(aF[m][1], b1F[n][1], acc[4 + m][2 + n]);
            }
        __builtin_amdgcn_s_setprio(0);
        __builtin_amdgcn_s_barrier();
        // ---- P3 ----
        if (t + 2 < NT) stage_half(1, cur, t + 2, 1);
        if (t + 1 < NT) {
            if (t + 2 < NT) asm volatile("s_waitcnt vmcnt(4)" ::: "memory");
            else            asm volatile("s_waitcnt vmcnt(0)" ::: "memory");
        }
        __builtin_amdgcn_s_barrier();
        __builtin_amdgcn_s_setprio(1);
#pragma unroll
        for (int m = 0; m < 4; m++)
#pragma unroll
            for (int n = 0; n < 2; n++) {
                acc[4 + m][n] = MFMA(aF[m][0], b0F[n][0], acc[4 + m][n]);
                acc[4 + m][n] = MFMA(aF[m][1], b0F[n][1], acc[4 + m][n]);
            }
        __builtin_amdgcn_s_setprio(0);
        __builtin_amdgcn_s_barrier();
    }
    u16* Cout = (KSPLITS == 2 && ksplit) ? Cb2 : Cb;
#pragma unroll
    for (int m = 0; m < 8; m++)
#pragma unroll
        for (int n = 0; n < 4; n++)
#pragma unroll
            for (int i = 0; i < 4; i++) {
                int rg = (int)row0 + wm * 128 + m * 16 + lg * 4 + i;
                int cg = col0 + wn * 64 + n * 16 + lr;
                float v = acc[m][n][i];
                if constexpr (EPI == 2) {
                    v += bias[cg];
                    v = v > 0.f ? v : 0.f;
                    Cout[(size_t)rg * N + cg] = f2bf(v);
                } else {
                    Cout[(size_t)rg * N + cg] = f2bf(v);
                }
            }
}

// ------- flash attention: 8-wave QBLK=256, 32x32 MFMA, in-reg P, amask -------
__global__ __launch_bounds__(512) void k_attn(const u16* __restrict__ qkv,
                                              const u16* __restrict__ vT,
                                              const u32* __restrict__ mbits,
                                              const u32* __restrict__ amask,
                                              u16* __restrict__ outb) {
    __shared__ u16 Kt[2][64 * 64];
    __shared__ u16 Vt[2][64 * 64];
    const int tid = threadIdx.x, lane = tid & 63, wave = tid >> 6;
    const int l31 = lane & 31, hi = lane >> 5;
    const int id0 = blockIdx.y * 8 + blockIdx.x;
    const int id = (id0 & 7) * 64 + (id0 >> 3);
    const int bh = id >> 3;
    const int b = bh >> 4, h = bh & 15;
    const int qb0 = (id & 7) * 256;
    const size_t qbase = (size_t)bh * (2048 * 64);
    const size_t kbase = (size_t)(64 + bh) * (2048 * 64);
    const size_t vtbase = (size_t)bh * (64 * 2048);

    bf16x8 qf[4];
    const int q0 = qb0 + wave * 32;
#pragma unroll
    for (int dstep = 0; dstep < 4; dstep++)
        qf[dstep] = *(const bf16x8*)(qkv + qbase + (size_t)(q0 + l31) * 64 +
                                     dstep * 16 + hi * 8);

    u16x8 ones_u;
#pragma unroll
    for (int e = 0; e < 8; e++) ones_u[e] = 0x3f80;
    const bf16x8 ones8 = *(const bf16x8*)&ones_u;

    f32x16 o0 = {}, o1 = {}, lacc = {};
    f32x16 zin;
#pragma unroll
    for (int r = 0; r < 16; r++) zin[r] = -16.f;

    // staging: thread -> (row = tid>>3, granule = tid&7); one u16x8 per K and V
    const int srow = tid >> 3, sg8 = tid & 7;
    const int swzs = (srow & 7) << 4;
    const int sb0 = srow * 128 + sg8 * 16;

    u16x8 krA, vrA;
    auto issue_loads = [&](int kv0n) {
        krA = *(const u16x8*)(qkv + kbase + (size_t)(kv0n + srow) * 64 + sg8 * 8);
        vrA = *(const u16x8*)(vT + vtbase + (size_t)srow * 2048 + kv0n + sg8 * 8);
    };
    auto write_tile = [&](int buf) {
        *(u16x8*)((char*)&Kt[buf][0] + (sb0 ^ swzs)) = krA;
        *(u16x8*)((char*)&Vt[buf][0] + (sb0 ^ swzs)) = vrA;
    };

    const u32 am = amask[b * 2048 + qb0 + wave * 32 + l31];
    const int rK0 = l31, rK1 = 32 + l31;
    const int swK0 = (rK0 & 7) << 4, swK1 = (rK1 & 7) << 4;

    issue_loads(0);
    write_tile(0);
    for (int t = 0; t < 32; ++t) {
        const int cur = t & 1;
        if (t + 1 < 32) issue_loads((t + 1) * 64);
        asm volatile("s_waitcnt lgkmcnt(0)" ::: "memory");
        __builtin_amdgcn_s_barrier();

        f32x16 st0 = zin, st1 = zin;
        __builtin_amdgcn_s_setprio(1);
#pragma unroll
        for (int dstep = 0; dstep < 4; dstep++) {
            bf16x8 kf0 = *(const bf16x8*)((char*)&Kt[cur][0] + rK0 * 128 +
                                          ((dstep * 32 + hi * 16) ^ swK0));
            bf16x8 kf1 = *(const bf16x8*)((char*)&Kt[cur][0] + rK1 * 128 +
                                          ((dstep * 32 + hi * 16) ^ swK1));
            st0 = MFMA32(kf0, qf[dstep], st0);
            st1 = MFMA32(kf1, qf[dstep], st1);
        }
        __builtin_amdgcn_s_setprio(0);

        if (!((am >> t) & 1u)) {  // cold path: exact per-element mask
            uint2 mw = *(const uint2*)&mbits[(size_t)(b * 2048 + qb0 + wave * 32 + l31) * 64 + 2 * t];
            u32 mw0 = mw.x >> (hi * 4), mw1 = mw.y >> (hi * 4);
#pragma unroll
            for (int r = 0; r < 16; r++) {
                int sh = (r & 3) + 8 * (r >> 2);
                if (!((mw0 >> sh) & 1u)) st0[r] = -1e9f;
                if (!((mw1 >> sh) & 1u)) st1[r] = -1e9f;
            }
        }
        bf16x8 pa[4];
#pragma unroll
        for (int r = 0; r < 16; r++) { st0[r] = v_exp2(st0[r]); st1[r] = v_exp2(st1[r]); }
#pragma unroll
        for (int kvb = 0; kvb < 2; kvb++) {
            const f32x16& st = kvb ? st1 : st0;
            u32 wA[4], wB[4];
#pragma unroll
            for (int g = 0; g < 4; g++) {
                wA[g] = cvt_pk_bf16(st[4 * g], st[4 * g + 1]);
                wB[g] = cvt_pk_bf16(st[4 * g + 2], st[4 * g + 3]);
            }
#pragma unroll
            for (int s = 0; s < 2; s++) {
                u32 xA = wA[2 * s], yA = wA[2 * s + 1];
                asm("v_permlane32_swap_b32 %0, %1" : "+v"(xA), "+v"(yA));
                u32 xB = wB[2 * s], yB = wB[2 * s + 1];
                asm("v_permlane32_swap_b32 %0, %1" : "+v"(xB), "+v"(yB));
                union { u32 w[4]; bf16x8 v; } pk;
                pk.w[0] = xA; pk.w[1] = xB; pk.w[2] = yA; pk.w[3] = yB;
                pa[kvb * 2 + s] = pk.v;
            }
        }
        __builtin_amdgcn_s_setprio(1);
#pragma unroll
        for (int ks = 0; ks < 4; ks++) {
            bf16x8 vb0 = *(const bf16x8*)((char*)&Vt[cur][0] + rK0 * 128 +
                                          ((ks * 32 + hi * 16) ^ swK0));
            bf16x8 vb1 = *(const bf16x8*)((char*)&Vt[cur][0] + rK1 * 128 +
                                          ((ks * 32 + hi * 16) ^ swK1));
            lacc = MFMA32(pa[ks], ones8, lacc);
            o0 = MFMA32(pa[ks], vb0, o0);
            o1 = MFMA32(pa[ks], vb1, o1);
        }
        __builtin_amdgcn_s_setprio(0);
        if (t + 1 < 32) write_tile(cur ^ 1);
    }
#pragma unroll
    for (int r = 0; r < 16; r++) {
        float inv = 1.f / lacc[r];
        int qg = qb0 + wave * 32 + (r & 3) + 8 * (r >> 2) + 4 * hi;
        size_t rowb = (size_t)(b * 2048 + qg) * 1024 + h * 64 + l31;
        outb[rowb] = f2bf(o0[r] * inv);
        outb[rowb + 32] = f2bf(o1[r] * inv);
    }
}

// ------- LayerNorm over bf16 input (residual pre-added), bf16 out -------
__global__ __launch_bounds__(256) void k_ln_b(const u16* __restrict__ tin,
                                              u16* __restrict__ outb,
                                              const float* __restrict__ alpha,
                                              const float* __restrict__ beta) {
    const int row = blockIdx.x, tid = threadIdx.x;
    const u16x4 tv = ((const u16x4*)(tin + (size_t)row * 1024))[tid];
    f32x4 t;
#pragma unroll
    for (int i = 0; i < 4; i++) t[i] = bf2f(tv[i]);
    float s = t[0] + t[1] + t[2] + t[3];
    float ss = t[0] * t[0] + t[1] * t[1] + t[2] * t[2] + t[3] * t[3];
#pragma unroll
    for (int m2 = 1; m2 < 64; m2 <<= 1) {
        s += __shfl_xor(s, m2);
        ss += __shfl_xor(ss, m2);
    }
    __shared__ float ps[4], pss[4];
    if ((tid & 63) == 0) { ps[tid >> 6] = s; pss[tid >> 6] = ss; }
    __syncthreads();
    s = ps[0] + ps[1] + ps[2] + ps[3];
    ss = pss[0] + pss[1] + pss[2] + pss[3];
    const float mean = s * (1.f / 1024.f);
    float var = (ss - 1024.f * mean * mean) * (1.f / 1023.f);
    var = fmaxf(var, 0.f);
    const float inv = alpha[0] / (sqrtf(var) + 1e-6f);
    const float bet = beta[0];
    u16x4 ob;
#pragma unroll
    for (int i = 0; i < 4; i++) ob[i] = f2bf((t[i] - mean) * inv + bet);
    ((u16x4*)(outb + (size_t)row * 1024))[tid] = ob;
}

// ------- LN over sum of two bf16 split-K partials + bias + bf16 residual -------
__global__ __launch_bounds__(256) void k_ln_sum2(const u16* __restrict__ p0,
                                                 const u16* __restrict__ p1,
                                                 const u16* __restrict__ residb,
                                                 const float* __restrict__ bias,
                                                 float* __restrict__ outf,
                                                 const float* __restrict__ alpha,
                                                 const float* __restrict__ beta) {
    const int row = blockIdx.x, tid = threadIdx.x;
    const u16x4 av = ((const u16x4*)(p0 + (size_t)row * 1024))[tid];
    const u16x4 cv = ((const u16x4*)(p1 + (size_t)row * 1024))[tid];
    const u16x4 rv = ((const u16x4*)(residb + (size_t)row * 1024))[tid];
    const f32x4 bb = ((const f32x4*)bias)[tid];
    f32x4 t;
#pragma unroll
    for (int i = 0; i < 4; i++) t[i] = bf2f(av[i]) + bf2f(cv[i]) + bf2f(rv[i]) + bb[i];
    float s = t[0] + t[1] + t[2] + t[3];
    float ss = t[0] * t[0] + t[1] * t[1] + t[2] * t[2] + t[3] * t[3];
#pragma unroll
    for (int m2 = 1; m2 < 64; m2 <<= 1) {
        s += __shfl_xor(s, m2);
        ss += __shfl_xor(ss, m2);
    }
    __shared__ float ps[4], pss[4];
    if ((tid & 63) == 0) { ps[tid >> 6] = s; pss[tid >> 6] = ss; }
    __syncthreads();
    s = ps[0] + ps[1] + ps[2] + ps[3];
    ss = pss[0] + pss[1] + pss[2] + pss[3];
    const float mean = s * (1.f / 1024.f);
    float var = (ss - 1024.f * mean * mean) * (1.f / 1023.f);
    var = fmaxf(var, 0.f);
    const float inv = alpha[0] / (sqrtf(var) + 1e-6f);
    const float bet = beta[0];
    f32x4 oo;
#pragma unroll
    for (int i = 0; i < 4; i++) oo[i] = (t[i] - mean) * inv + bet;
    ((f32x4*)(outf + (size_t)row * 1024))[tid] = oo;
}

// ---------------- launch ----------------
extern "C" void kernel_launch(void* const* d_in, const int* in_sizes, int n_in,
                              void* d_out, int out_size, void* d_ws, size_t ws_size,
                              hipStream_t stream) {
    const float* x   = (const float*)d_in[0];
    const int*   msk = (const int*)d_in[1];
    const float* wq  = (const float*)d_in[2];
    const float* wk  = (const float*)d_in[3];
    const float* wv  = (const float*)d_in[4];
    const float* wo  = (const float*)d_in[5];
    const float* w1  = (const float*)d_in[6];
    const float* b1  = (const float*)d_in[7];
    const float* w2  = (const float*)d_in[8];
    const float* b2  = (const float*)d_in[9];
    const float* a1  = (const float*)d_in[10];
    const float* bt1 = (const float*)d_in[11];
    const float* a2  = (const float*)d_in[12];
    const float* bt2 = (const float*)d_in[13];
    float* out = (float*)d_out;

    char* ws = (char*)d_ws;
    size_t off = 0;
    auto alloc = [&](size_t bytes) {
        void* p = ws + off;
        off += (bytes + 255) & ~(size_t)255;
        return p;
    };
    u16* xb    = (u16*)alloc((size_t)M_ * D_ * 2);
    u16* wqkvT = (u16*)alloc((size_t)3 * D_ * D_ * 2);  // contiguous with woT
    u16* woT   = (u16*)alloc((size_t)D_ * D_ * 2);
    u16* w1T   = (u16*)alloc((size_t)DFF_ * D_ * 2);
    u16* w2T   = (u16*)alloc((size_t)D_ * DFF_ * 2);
    u32* mbits = (u32*)alloc((size_t)B_ * S_ * 64 * 4);
    u32* amsk  = (u32*)alloc((size_t)B_ * S_ * 4);
    u16* aout  = (u16*)alloc((size_t)M_ * D_ * 2);
    u16* yb    = (u16*)alloc((size_t)M_ * D_ * 2);     // WO out + resid, bf16
    u16* y0b   = (u16*)alloc((size_t)M_ * D_ * 2);     // FFN2 partial 0, bf16
    u16* y1b   = (u16*)alloc((size_t)M_ * D_ * 2);     // FFN2 partial 1, bf16
    u16* x1b   = (u16*)alloc((size_t)M_ * D_ * 2);     // LN1 out, bf16
    u16* vTb   = (u16*)alloc((size_t)64 * 64 * 2048 * 2);
    u16* qkv   = (u16*)alloc((size_t)M_ * DFF_ * 2);
    u16* hft   = qkv;

    // 1) pre-pass
    k_pack_amask<<<dim3((B_ * S_) / 4), 256, 0, stream>>>(msk, mbits, amsk);
    k_cast_bf16<<<dim3((M_ * D_ / 4) / 256), 256, 0, stream>>>(x, xb, M_ * D_ / 4);
    dim3 tb(32, 8);
    k_transpose_cast4<<<dim3(32, 32, 4), tb, 0, stream>>>(wq, wk, wv, wo, wqkvT);
    k_transpose_cast<<<dim3(128, 32), tb, 0, stream>>>(w1, w1T, D_, DFF_);
    k_transpose_cast<<<dim3(32, 128), tb, 0, stream>>>(w2, w2T, DFF_, D_);

    // 2) QKV projection (128^2, 1536 blocks); V written transposed into vTb.
    k_gemm8<0><<<dim3(1536), 512, 0, stream>>>(xb, wqkvT, qkv, nullptr,
                                               nullptr, vTb, 3 * D_, D_);
    // 3) flash attention (8-wave, QBLK=256, 512 blocks)
    k_attn<<<dim3(8, 64), 512, 0, stream>>>(qkv, vTb, mbits, amsk, aout);
    // 4) output projection + bf16 residual -> yb (bf16)
    k_gemm8<1><<<dim3(512), 512, 0, stream>>>(aout, woT, yb, nullptr, xb,
                                              nullptr, D_, D_);
    // 5) LN1 (bf16 in/out)
    k_ln_b<<<dim3(M_), 256, 0, stream>>>(yb, x1b, a1, bt1);
    // 6) FFN1 (256^2 4-phase, 512 blocks)
    k_gemm256<2, 1><<<dim3(512), 512, 0, stream>>>(x1b, w1T, hft, nullptr,
                                                   b1, DFF_, D_, D_);
    // 7) FFN2 split-K=2 (256 blocks): bf16 partials y0b, y1b
    k_gemm256<3, 2><<<dim3(256), 512, 0, stream>>>(hft, w2T, y0b, y1b,
                                                   nullptr, D_, DFF_ / 2, DFF_);
    // 8) LN2 over (y0b + y1b + b2 + x1b) -> d_out
    k_ln_sum2<<<dim3(M_), 256, 0, stream>>>(y0b, y1b, x1b, b2, out, a2, bt2);
}

// Round 16
// 367.820 us; speedup vs baseline: 1.0291x; 1.0105x over previous
//
#include <hip/hip_runtime.h>
#include <stdint.h>

typedef __bf16 bf16x8 __attribute__((ext_vector_type(8)));
typedef float f32x4 __attribute__((ext_vector_type(4)));
typedef float f32x16 __attribute__((ext_vector_type(16)));
typedef unsigned short u16;
typedef u16 u16x8 __attribute__((ext_vector_type(8)));
typedef u16 u16x4 __attribute__((ext_vector_type(4)));
typedef uint32_t u32;

#define DEV __device__ __forceinline__
#define MFMA(a, b, c) __builtin_amdgcn_mfma_f32_16x16x32_bf16(a, b, c, 0, 0, 0)
#define MFMA32(a, b, c) __builtin_amdgcn_mfma_f32_32x32x16_bf16(a, b, c, 0, 0, 0)

static constexpr int B_ = 4, S_ = 2048, M_ = 8192, D_ = 1024, H_ = 16, DFF_ = 4096;

DEV u16 f2bf(float f) {
    union { float f; u32 u; } c; c.f = f;
    u32 u = c.u;
    return (u16)((u + 0x7fffu + ((u >> 16) & 1u)) >> 16);
}

DEV float bf2f(u16 v) {
    union { u32 u; float f; } c; c.u = (u32)v << 16;
    return c.f;
}

DEV u32 cvt_pk_bf16(float lo, float hi) {
    u32 r;
    asm("v_cvt_pk_bf16_f32 %0, %1, %2" : "=v"(r) : "v"(lo), "v"(hi));
    return r;
}

DEV float v_exp2(float x) {  // raw 2^x
    float r;
    asm("v_exp_f32 %0, %1" : "=v"(r) : "v"(x));
    return r;
}

DEV void gload16(void* lds, const void* g) {
    __builtin_amdgcn_global_load_lds(
        (const __attribute__((address_space(1))) unsigned int*)g,
        (__attribute__((address_space(3))) unsigned int*)lds, 16, 0, 0);
}

// ---------------- fused pre-pass #1: mask pack + amask + x cast ----------------
// blocks [0,2048): mask pack (wave per row, 4 rows/block) + tile-allones bitmap
// blocks [2048,10240): x f32 -> bf16 cast (f32x4 per thread)
__global__ __launch_bounds__(256) void k_prep(const int* __restrict__ m,
                                              u32* __restrict__ bits,
                                              u32* __restrict__ am,
                                              const float* __restrict__ x,
                                              u16* __restrict__ xb) {
    const int blk = blockIdx.x;
    if (blk < 2048) {
        const int lane = threadIdx.x & 63, wv = threadIdx.x >> 6;
        const int row = blk * 4 + wv;
        const int4* s = (const int4*)(m + ((size_t)row * 64 + lane) * 32);
        u32 r = 0;
#pragma unroll
        for (int j = 0; j < 8; j++) {
            int4 v = s[j];
            r |= (u32)(v.x != 0) << (j * 4) | (u32)(v.y != 0) << (j * 4 + 1) |
                 (u32)(v.z != 0) << (j * 4 + 2) | (u32)(v.w != 0) << (j * 4 + 3);
        }
        bits[(size_t)row * 64 + lane] = r;
        unsigned long long b = __ballot(r == 0xffffffffu);
        if (lane == 0) {
            u32 a = 0;
#pragma unroll
            for (int t = 0; t < 32; t++)
                a |= (u32)(((b >> (2 * t)) & 3ull) == 3ull) << t;
            am[row] = a;
        }
    } else {
        const int i = (blk - 2048) * 256 + threadIdx.x;
        f32x4 v = ((const f32x4*)x)[i];
        u16x4 o;
        o[0] = f2bf(v[0]); o[1] = f2bf(v[1]); o[2] = f2bf(v[2]); o[3] = f2bf(v[3]);
        ((u16x4*)xb)[i] = o;
    }
}

// ---------------- fused pre-pass #2: all weight transposes ----------------
// blocks [0,4096): wq/wk/wv/wo DxD (1024 tiles each) -> wqkvT (+woT contiguous)
// blocks [4096,8192): w1 [1024][4096] -> w1T [4096][1024]
// blocks [8192,12288): w2 [4096][1024] -> w2T [1024][4096]
__global__ __launch_bounds__(256) void k_wt(const float* __restrict__ wq,
                                            const float* __restrict__ wk,
                                            const float* __restrict__ wv,
                                            const float* __restrict__ wo,
                                            const float* __restrict__ w1,
                                            const float* __restrict__ w2,
                                            u16* __restrict__ wqkvT,
                                            u16* __restrict__ w1T,
                                            u16* __restrict__ w2T) {
    __shared__ float t[32][33];
    const int blk = blockIdx.x;
    const float* s;
    u16* d;
    int K, N, n0, k0;
    if (blk < 4096) {
        const int wid = blk >> 10, tt = blk & 1023;
        s = (wid == 0) ? wq : (wid == 1) ? wk : (wid == 2) ? wv : wo;
        d = wqkvT + (size_t)wid * D_ * D_;  // woT contiguous after wqkvT
        K = D_; N = D_;
        n0 = (tt & 31) * 32; k0 = (tt >> 5) * 32;
    } else if (blk < 8192) {
        const int tt = blk - 4096;
        s = w1; d = w1T; K = D_; N = DFF_;
        n0 = (tt & 127) * 32; k0 = (tt >> 7) * 32;
    } else {
        const int tt = blk - 8192;
        s = w2; d = w2T; K = DFF_; N = D_;
        n0 = (tt & 31) * 32; k0 = (tt >> 5) * 32;
    }
    const int tx = threadIdx.x & 31, ty = threadIdx.x >> 5;
#pragma unroll
    for (int i = 0; i < 4; i++)
        t[ty + i * 8][tx] = s[(size_t)(k0 + ty + i * 8) * N + n0 + tx];
    __syncthreads();
#pragma unroll
    for (int i = 0; i < 4; i++)
        d[(size_t)(n0 + ty + i * 8) * K + k0 + tx] = f2bf(t[tx][ty + i * 8]);
}

// ---- 128x128 8-wave GEMM, BK=64, dbuf LDS, counted vmcnt, T2 swizzle ----
// EPI 0: QKV scatter (Q scaled by 0.125*log2e; V written transposed to Vt)
// EPI 1: +bf16 resid, bf16 out; EPI 2: +bias relu bf16
template <int EPI>
__global__ __launch_bounds__(512, 4) void k_gemm8(const u16* __restrict__ A,
                                                  const u16* __restrict__ Bt,
                                                  u16* __restrict__ Cb,
                                                  const float* __restrict__ bias,
                                                  const u16* __restrict__ residb,
                                                  u16* __restrict__ Vt,
                                                  int N, int K) {
    __shared__ u16 As[2][128 * 64];
    __shared__ u16 Bs[2][128 * 64];
    const int tid = threadIdx.x, lane = tid & 63, wave = tid >> 6;
    const int lr = lane & 15, lg = lane >> 4;
    const int wm = wave >> 1, wn = wave & 1;
    const int nbx = N >> 7;
    const int chunk = gridDim.x >> 3;
    const int id = ((int)blockIdx.x & 7) * chunk + ((int)blockIdx.x >> 3);
    const size_t row0 = (size_t)(id / nbx) * 128;
    const int col0 = (id % nbx) * 128;
    const int srow = lane >> 3;
    const int sgr = (lane & 7) ^ srow;
    const int NT = K >> 6;
    f32x4 acc[2][4] = {};

    auto stage = [&](int buf, int t) {
#pragma unroll
        for (int i = 0; i < 2; i++) {
            int c = i * 8 + wave;
            gload16((char*)&As[buf][0] + c * 1024,
                    (const char*)(A + (row0 + c * 8 + srow) * K + t * 64 + sgr * 8));
        }
#pragma unroll
        for (int i = 0; i < 2; i++) {
            int c = i * 8 + wave;
            gload16((char*)&Bs[buf][0] + c * 1024,
                    (const char*)(Bt + (size_t)(col0 + c * 8 + srow) * K + t * 64 + sgr * 8));
        }
    };

    stage(0, 0);
    for (int t = 0; t < NT; ++t) {
        const int cur = t & 1;
        if (t + 1 < NT) {
            stage(cur ^ 1, t + 1);
            asm volatile("s_waitcnt vmcnt(4)" ::: "memory");
        } else {
            asm volatile("s_waitcnt vmcnt(0)" ::: "memory");
        }
        __builtin_amdgcn_s_barrier();
        asm volatile("" ::: "memory");
        bf16x8 bF[4][2];
#pragma unroll
        for (int n = 0; n < 4; n++) {
            int r = wn * 64 + n * 16 + lr;
            int rb = r * 128, sw = (r & 7) << 4;
#pragma unroll
            for (int ks = 0; ks < 2; ks++)
                bF[n][ks] = *(const bf16x8*)((char*)&Bs[cur][0] +
                                             (rb + ((ks * 64 + lg * 16) ^ sw)));
        }
#pragma unroll
        for (int m = 0; m < 2; m++) {
            int r = wm * 32 + m * 16 + lr;
            int rb = r * 128, sw = (r & 7) << 4;
            bf16x8 a0 = *(const bf16x8*)((char*)&As[cur][0] + (rb + ((lg * 16) ^ sw)));
            bf16x8 a1 = *(const bf16x8*)((char*)&As[cur][0] + (rb + ((64 + lg * 16) ^ sw)));
            __builtin_amdgcn_s_setprio(1);
#pragma unroll
            for (int n = 0; n < 4; n++) {
                acc[m][n] = MFMA(a0, bF[n][0], acc[m][n]);
                acc[m][n] = MFMA(a1, bF[n][1], acc[m][n]);
            }
            __builtin_amdgcn_s_setprio(0);
        }
        asm volatile("" ::: "memory");
        __builtin_amdgcn_s_barrier();
    }
#pragma unroll
    for (int m = 0; m < 2; m++)
#pragma unroll
        for (int n = 0; n < 4; n++) {
            const int cg = col0 + wn * 64 + n * 16 + lr;
            const int rbase = (int)row0 + wm * 32 + m * 16 + lg * 4;
            if constexpr (EPI == 0) {
                const int proj = cg >> 10, hh = (cg >> 6) & 15, dk = cg & 63;
                const int b = rbase >> 11, s = rbase & 2047;
                if (proj == 2) {  // V: write transposed, vT[b*16+hh][dk][s..s+3]
                    u16x4 ov;
#pragma unroll
                    for (int i = 0; i < 4; i++) ov[i] = f2bf(acc[m][n][i]);
                    *(u16x4*)(Vt + ((size_t)(b * 16 + hh) * 64 + dk) * 2048 + s) = ov;
                } else {
                    const float sc = (proj == 0) ? 0.1803368801111832f : 1.f;
                    size_t base = ((size_t)(proj * 64 + b * 16 + hh) * 2048 + s) * 64 + dk;
#pragma unroll
                    for (int i = 0; i < 4; i++)
                        Cb[base + (size_t)i * 64] = f2bf(acc[m][n][i] * sc);
                }
            } else {
#pragma unroll
                for (int i = 0; i < 4; i++) {
                    const int rg = rbase + i;
                    float v = acc[m][n][i];
                    if constexpr (EPI == 1) {
                        Cb[(size_t)rg * N + cg] =
                            f2bf(v + bf2f(residb[(size_t)rg * N + cg]));
                    } else {
                        v += bias[cg];
                        v = v > 0.f ? v : 0.f;
                        Cb[(size_t)rg * N + cg] = f2bf(v);
                    }
                }
            }
        }
}

// ---- 256x256 8-wave 4-phase GEMM, BK=64, dbuf LDS, counted vmcnt ----
// EPI 2: +bias relu bf16 ; EPI 3: bf16 split-K partial store
template <int EPI, int KSPLITS>
__global__ __launch_bounds__(512, 2) void k_gemm256(const u16* __restrict__ A,
                                                    const u16* __restrict__ Bt,
                                                    u16* __restrict__ Cb,
                                                    u16* __restrict__ Cb2,
                                                    const float* __restrict__ bias,
                                                    int N, int Keff, int lda) {
    __shared__ u16 As[2][256 * 64];
    __shared__ u16 Bs[2][256 * 64];
    const int tid = threadIdx.x, lane = tid & 63, wave = tid >> 6;
    const int lr = lane & 15, lg = lane >> 4;
    const int wm = wave >> 2, wn = wave & 3;
    const int nbx = N >> 8;
    const int chunk = gridDim.x >> 3;
    const int id = ((int)blockIdx.x & 7) * chunk + ((int)blockIdx.x >> 3);
    int tileid = id, ksplit = 0;
    if constexpr (KSPLITS == 2) { ksplit = id & 1; tileid = id >> 1; }
    const int kof = ksplit * Keff;
    const size_t row0 = (size_t)(tileid / nbx) * 256;
    const int col0 = (tileid % nbx) * 256;
    const int srow = lane >> 3;
    const int sgr = (lane & 7) ^ srow;
    const int NT = Keff >> 6;
    f32x4 acc[8][4] = {};

    auto stage_half = [&](int isB, int buf, int t, int h) {
        const u16* g = isB ? Bt : A;
        const size_t grow0 = isB ? (size_t)col0 : row0;
        char* base = isB ? (char*)&Bs[buf][0] : (char*)&As[buf][0];
#pragma unroll
        for (int l = 0; l < 2; l++) {
            int rt = h * 128 + l * 64 + wave * 8;
            gload16(base + rt * 128,
                    (const char*)(g + (grow0 + rt + srow) * lda + kof + t * 64 + sgr * 8));
        }
    };
    auto rdA = [&](int cur, int mh, int m, int kk) -> bf16x8 {
        int r = wm * 128 + mh * 64 + m * 16 + lr;
        int gi = kk * 4 + lg;
        return *(const bf16x8*)((char*)&As[cur][0] + r * 128 + ((gi ^ (r & 7)) << 4));
    };
    auto rdB = [&](int cur, int nh, int n, int kk) -> bf16x8 {
        int r = wn * 64 + nh * 32 + n * 16 + lr;
        int gi = kk * 4 + lg;
        return *(const bf16x8*)((char*)&Bs[cur][0] + r * 128 + ((gi ^ (r & 7)) << 4));
    };

    stage_half(0, 0, 0, 0); stage_half(0, 0, 0, 1);
    stage_half(1, 0, 0, 0); stage_half(1, 0, 0, 1);
    stage_half(1, 1, 1, 0); stage_half(1, 1, 1, 1);
    asm volatile("s_waitcnt vmcnt(4)" ::: "memory");
    __builtin_amdgcn_s_barrier();

    bf16x8 aF[4][2], b0F[2][2], b1F[2][2];
    for (int t = 0; t < NT; ++t) {
        const int cur = t & 1, nxt = cur ^ 1;
        // ---- P0 ----
#pragma unroll
        for (int m = 0; m < 4; m++) { aF[m][0] = rdA(cur, 0, m, 0); aF[m][1] = rdA(cur, 0, m, 1); }
#pragma unroll
        for (int n = 0; n < 2; n++) { b0F[n][0] = rdB(cur, 0, n, 0); b0F[n][1] = rdB(cur, 0, n, 1); }
        if (t + 1 < NT) stage_half(0, nxt, t + 1, 0);
        __builtin_amdgcn_s_barrier();
        asm volatile("s_waitcnt lgkmcnt(0)" ::: "memory");
        __builtin_amdgcn_sched_barrier(0);
        __builtin_amdgcn_s_setprio(1);
#pragma unroll
        for (int m = 0; m < 4; m++)
#pragma unroll
            for (int n = 0; n < 2; n++) {
                acc[m][n] = MFMA(aF[m][0], b0F[n][0], acc[m][n]);
                acc[m][n] = MFMA(aF[m][1], b0F[n][1], acc[m][n]);
            }
        __builtin_amdgcn_s_setprio(0);
        __builtin_amdgcn_s_barrier();
        // ---- P1 ----
#pragma unroll
        for (int n = 0; n < 2; n++) { b1F[n][0] = rdB(cur, 1, n, 0); b1F[n][1] = rdB(cur, 1, n, 1); }
        if (t + 1 < NT) stage_half(0, nxt, t + 1, 1);
        __builtin_amdgcn_s_barrier();
        asm volatile("s_waitcnt lgkmcnt(0)" ::: "memory");
        __builtin_amdgcn_sched_barrier(0);
        __builtin_amdgcn_s_setprio(1);
#pragma unroll
        for (int m = 0; m < 4; m++)
#pragma unroll
            for (int n = 0; n < 2; n++) {
                acc[m][2 + n] = MFMA(aF[m][0], b1F[n][0], acc[m][2 + n]);
                acc[m][2 + n] = MFMA(aF[m][1], b1F[n][1], acc[m][2 + n]);
            }
        __builtin_amdgcn_s_setprio(0);
        __builtin_amdgcn_s_barrier();
        // ---- P2 ----
#pragma unroll
        for (int m = 0; m < 4; m++) { aF[m][0] = rdA(cur, 1, m, 0); aF[m][1] = rdA(cur, 1, m, 1); }
        if (t + 2 < NT) stage_half(1, cur, t + 2, 0);
        __builtin_amdgcn_s_barrier();
        asm volatile("s_waitcnt lgkmcnt(0)" ::: "memory");
        __builtin_amdgcn_sched_barrier(0);
        __builtin_amdgcn_s_setprio(1);
#pragma unroll
        for (int m = 0; m < 4; m++)
#pragma unroll
            for (int n = 0; n < 2; n++) {
                acc[4 + m][2 + n] = MFMA(aF[m][0], b1F[n][0], acc[4 + m][2 + n]);
                acc[4 + m][2 + n] = MFMA(aF[m][1], b1F[n][1], acc[4 + m][2 + n]);
            }
        __builtin_amdgcn_s_setprio(0);
        __builtin_amdgcn_s_barrier();
        // ---- P3 ----
        if (t + 2 < NT) stage_half(1, cur, t + 2, 1);
        if (t + 1 < NT) {
            if (t + 2 < NT) asm volatile("s_waitcnt vmcnt(4)" ::: "memory");
            else            asm volatile("s_waitcnt vmcnt(0)" ::: "memory");
        }
        __builtin_amdgcn_s_barrier();
        __builtin_amdgcn_s_setprio(1);
#pragma unroll
        for (int m = 0; m < 4; m++)
#pragma unroll
            for (int n = 0; n < 2; n++) {
                acc[4 + m][n] = MFMA(aF[m][0], b0F[n][0], acc[4 + m][n]);
                acc[4 + m][n] = MFMA(aF[m][1], b0F[n][1], acc[4 + m][n]);
            }
        __builtin_amdgcn_s_setprio(0);
        __builtin_amdgcn_s_barrier();
    }
    u16* Cout = (KSPLITS == 2 && ksplit) ? Cb2 : Cb;
#pragma unroll
    for (int m = 0; m < 8; m++)
#pragma unroll
        for (int n = 0; n < 4; n++)
#pragma unroll
            for (int i = 0; i < 4; i++) {
                int rg = (int)row0 + wm * 128 + m * 16 + lg * 4 + i;
                int cg = col0 + wn * 64 + n * 16 + lr;
                float v = acc[m][n][i];
                if constexpr (EPI == 2) {
                    v += bias[cg];
                    v = v > 0.f ? v : 0.f;
                    Cout[(size_t)rg * N + cg] = f2bf(v);
                } else {
                    Cout[(size_t)rg * N + cg] = f2bf(v);
                }
            }
}

// ------- flash attention: 8-wave QBLK=256, 32x32 MFMA, in-reg P, amask -------
__global__ __launch_bounds__(512) void k_attn(const u16* __restrict__ qkv,
                                              const u16* __restrict__ vT,
                                              const u32* __restrict__ mbits,
                                              const u32* __restrict__ amask,
                                              u16* __restrict__ outb) {
    __shared__ u16 Kt[2][64 * 64];
    __shared__ u16 Vt[2][64 * 64];
    const int tid = threadIdx.x, lane = tid & 63, wave = tid >> 6;
    const int l31 = lane & 31, hi = lane >> 5;
    const int id0 = blockIdx.y * 8 + blockIdx.x;
    const int id = (id0 & 7) * 64 + (id0 >> 3);
    const int bh = id >> 3;
    const int b = bh >> 4, h = bh & 15;
    const int qb0 = (id & 7) * 256;
    const size_t qbase = (size_t)bh * (2048 * 64);
    const size_t kbase = (size_t)(64 + bh) * (2048 * 64);
    const size_t vtbase = (size_t)bh * (64 * 2048);

    bf16x8 qf[4];
    const int q0 = qb0 + wave * 32;
#pragma unroll
    for (int dstep = 0; dstep < 4; dstep++)
        qf[dstep] = *(const bf16x8*)(qkv + qbase + (size_t)(q0 + l31) * 64 +
                                     dstep * 16 + hi * 8);

    u16x8 ones_u;
#pragma unroll
    for (int e = 0; e < 8; e++) ones_u[e] = 0x3f80;
    const bf16x8 ones8 = *(const bf16x8*)&ones_u;

    f32x16 o0 = {}, o1 = {}, lacc = {};
    f32x16 zin;
#pragma unroll
    for (int r = 0; r < 16; r++) zin[r] = -16.f;

    // staging: thread -> (row = tid>>3, granule = tid&7); one u16x8 per K and V
    const int srow = tid >> 3, sg8 = tid & 7;
    const int swzs = (srow & 7) << 4;
    const int sb0 = srow * 128 + sg8 * 16;

    u16x8 krA, vrA;
    auto issue_loads = [&](int kv0n) {
        krA = *(const u16x8*)(qkv + kbase + (size_t)(kv0n + srow) * 64 + sg8 * 8);
        vrA = *(const u16x8*)(vT + vtbase + (size_t)srow * 2048 + kv0n + sg8 * 8);
    };
    auto write_tile = [&](int buf) {
        *(u16x8*)((char*)&Kt[buf][0] + (sb0 ^ swzs)) = krA;
        *(u16x8*)((char*)&Vt[buf][0] + (sb0 ^ swzs)) = vrA;
    };

    const u32 am = amask[b * 2048 + qb0 + wave * 32 + l31];
    const int rK0 = l31, rK1 = 32 + l31;
    const int swK0 = (rK0 & 7) << 4, swK1 = (rK1 & 7) << 4;

    issue_loads(0);
    write_tile(0);
    for (int t = 0; t < 32; ++t) {
        const int cur = t & 1;
        if (t + 1 < 32) issue_loads((t + 1) * 64);
        asm volatile("s_waitcnt lgkmcnt(0)" ::: "memory");
        __builtin_amdgcn_s_barrier();

        f32x16 st0 = zin, st1 = zin;
        __builtin_amdgcn_s_setprio(1);
#pragma unroll
        for (int dstep = 0; dstep < 4; dstep++) {
            bf16x8 kf0 = *(const bf16x8*)((char*)&Kt[cur][0] + rK0 * 128 +
                                          ((dstep * 32 + hi * 16) ^ swK0));
            bf16x8 kf1 = *(const bf16x8*)((char*)&Kt[cur][0] + rK1 * 128 +
                                          ((dstep * 32 + hi * 16) ^ swK1));
            st0 = MFMA32(kf0, qf[dstep], st0);
            st1 = MFMA32(kf1, qf[dstep], st1);
        }
        __builtin_amdgcn_s_setprio(0);

        if (!((am >> t) & 1u)) {  // cold path: exact per-element mask
            uint2 mw = *(const uint2*)&mbits[(size_t)(b * 2048 + qb0 + wave * 32 + l31) * 64 + 2 * t];
            u32 mw0 = mw.x >> (hi * 4), mw1 = mw.y >> (hi * 4);
#pragma unroll
            for (int r = 0; r < 16; r++) {
                int sh = (r & 3) + 8 * (r >> 2);
                if (!((mw0 >> sh) & 1u)) st0[r] = -1e9f;
                if (!((mw1 >> sh) & 1u)) st1[r] = -1e9f;
            }
        }
        bf16x8 pa[4];
#pragma unroll
        for (int r = 0; r < 16; r++) { st0[r] = v_exp2(st0[r]); st1[r] = v_exp2(st1[r]); }
#pragma unroll
        for (int kvb = 0; kvb < 2; kvb++) {
            const f32x16& st = kvb ? st1 : st0;
            u32 wA[4], wB[4];
#pragma unroll
            for (int g = 0; g < 4; g++) {
                wA[g] = cvt_pk_bf16(st[4 * g], st[4 * g + 1]);
                wB[g] = cvt_pk_bf16(st[4 * g + 2], st[4 * g + 3]);
            }
#pragma unroll
            for (int s = 0; s < 2; s++) {
                u32 xA = wA[2 * s], yA = wA[2 * s + 1];
                asm("v_permlane32_swap_b32 %0, %1" : "+v"(xA), "+v"(yA));
                u32 xB = wB[2 * s], yB = wB[2 * s + 1];
                asm("v_permlane32_swap_b32 %0, %1" : "+v"(xB), "+v"(yB));
                union { u32 w[4]; bf16x8 v; } pk;
                pk.w[0] = xA; pk.w[1] = xB; pk.w[2] = yA; pk.w[3] = yB;
                pa[kvb * 2 + s] = pk.v;
            }
        }
        __builtin_amdgcn_s_setprio(1);
#pragma unroll
        for (int ks = 0; ks < 4; ks++) {
            bf16x8 vb0 = *(const bf16x8*)((char*)&Vt[cur][0] + rK0 * 128 +
                                          ((ks * 32 + hi * 16) ^ swK0));
            bf16x8 vb1 = *(const bf16x8*)((char*)&Vt[cur][0] + rK1 * 128 +
                                          ((ks * 32 + hi * 16) ^ swK1));
            lacc = MFMA32(pa[ks], ones8, lacc);
            o0 = MFMA32(pa[ks], vb0, o0);
            o1 = MFMA32(pa[ks], vb1, o1);
        }
        __builtin_amdgcn_s_setprio(0);
        if (t + 1 < 32) write_tile(cur ^ 1);
    }
#pragma unroll
    for (int r = 0; r < 16; r++) {
        float inv = 1.f / lacc[r];
        int qg = qb0 + wave * 32 + (r & 3) + 8 * (r >> 2) + 4 * hi;
        size_t rowb = (size_t)(b * 2048 + qg) * 1024 + h * 64 + l31;
        outb[rowb] = f2bf(o0[r] * inv);
        outb[rowb + 32] = f2bf(o1[r] * inv);
    }
}

// ------- LayerNorm over bf16 input (residual pre-added), bf16 out -------
__global__ __launch_bounds__(256) void k_ln_b(const u16* __restrict__ tin,
                                              u16* __restrict__ outb,
                                              const float* __restrict__ alpha,
                                              const float* __restrict__ beta) {
    const int row = blockIdx.x, tid = threadIdx.x;
    const u16x4 tv = ((const u16x4*)(tin + (size_t)row * 1024))[tid];
    f32x4 t;
#pragma unroll
    for (int i = 0; i < 4; i++) t[i] = bf2f(tv[i]);
    float s = t[0] + t[1] + t[2] + t[3];
    float ss = t[0] * t[0] + t[1] * t[1] + t[2] * t[2] + t[3] * t[3];
#pragma unroll
    for (int m2 = 1; m2 < 64; m2 <<= 1) {
        s += __shfl_xor(s, m2);
        ss += __shfl_xor(ss, m2);
    }
    __shared__ float ps[4], pss[4];
    if ((tid & 63) == 0) { ps[tid >> 6] = s; pss[tid >> 6] = ss; }
    __syncthreads();
    s = ps[0] + ps[1] + ps[2] + ps[3];
    ss = pss[0] + pss[1] + pss[2] + pss[3];
    const float mean = s * (1.f / 1024.f);
    float var = (ss - 1024.f * mean * mean) * (1.f / 1023.f);
    var = fmaxf(var, 0.f);
    const float inv = alpha[0] / (sqrtf(var) + 1e-6f);
    const float bet = beta[0];
    u16x4 ob;
#pragma unroll
    for (int i = 0; i < 4; i++) ob[i] = f2bf((t[i] - mean) * inv + bet);
    ((u16x4*)(outb + (size_t)row * 1024))[tid] = ob;
}

// ------- LN over sum of two bf16 split-K partials + bias + bf16 residual -------
__global__ __launch_bounds__(256) void k_ln_sum2(const u16* __restrict__ p0,
                                                 const u16* __restrict__ p1,
                                                 const u16* __restrict__ residb,
                                                 const float* __restrict__ bias,
                                                 float* __restrict__ outf,
                                                 const float* __restrict__ alpha,
                                                 const float* __restrict__ beta) {
    const int row = blockIdx.x, tid = threadIdx.x;
    const u16x4 av = ((const u16x4*)(p0 + (size_t)row * 1024))[tid];
    const u16x4 cv = ((const u16x4*)(p1 + (size_t)row * 1024))[tid];
    const u16x4 rv = ((const u16x4*)(residb + (size_t)row * 1024))[tid];
    const f32x4 bb = ((const f32x4*)bias)[tid];
    f32x4 t;
#pragma unroll
    for (int i = 0; i < 4; i++) t[i] = bf2f(av[i]) + bf2f(cv[i]) + bf2f(rv[i]) + bb[i];
    float s = t[0] + t[1] + t[2] + t[3];
    float ss = t[0] * t[0] + t[1] * t[1] + t[2] * t[2] + t[3] * t[3];
#pragma unroll
    for (int m2 = 1; m2 < 64; m2 <<= 1) {
        s += __shfl_xor(s, m2);
        ss += __shfl_xor(ss, m2);
    }
    __shared__ float ps[4], pss[4];
    if ((tid & 63) == 0) { ps[tid >> 6] = s; pss[tid >> 6] = ss; }
    __syncthreads();
    s = ps[0] + ps[1] + ps[2] + ps[3];
    ss = pss[0] + pss[1] + pss[2] + pss[3];
    const float mean = s * (1.f / 1024.f);
    float var = (ss - 1024.f * mean * mean) * (1.f / 1023.f);
    var = fmaxf(var, 0.f);
    const float inv = alpha[0] / (sqrtf(var) + 1e-6f);
    const float bet = beta[0];
    f32x4 oo;
#pragma unroll
    for (int i = 0; i < 4; i++) oo[i] = (t[i] - mean) * inv + bet;
    ((f32x4*)(outf + (size_t)row * 1024))[tid] = oo;
}

// ---------------- launch ----------------
extern "C" void kernel_launch(void* const* d_in, const int* in_sizes, int n_in,
                              void* d_out, int out_size, void* d_ws, size_t ws_size,
                              hipStream_t stream) {
    const float* x   = (const float*)d_in[0];
    const int*   msk = (const int*)d_in[1];
    const float* wq  = (const float*)d_in[2];
    const float* wk  = (const float*)d_in[3];
    const float* wv  = (const float*)d_in[4];
    const float* wo  = (const float*)d_in[5];
    const float* w1  = (const float*)d_in[6];
    const float* b1  = (const float*)d_in[7];
    const float* w2  = (const float*)d_in[8];
    const float* b2  = (const float*)d_in[9];
    const float* a1  = (const float*)d_in[10];
    const float* bt1 = (const float*)d_in[11];
    const float* a2  = (const float*)d_in[12];
    const float* bt2 = (const float*)d_in[13];
    float* out = (float*)d_out;

    char* ws = (char*)d_ws;
    size_t off = 0;
    auto alloc = [&](size_t bytes) {
        void* p = ws + off;
        off += (bytes + 255) & ~(size_t)255;
        return p;
    };
    u16* xb    = (u16*)alloc((size_t)M_ * D_ * 2);
    u16* wqkvT = (u16*)alloc((size_t)3 * D_ * D_ * 2);  // contiguous with woT (k_wt relies on it)
    u16* woT   = (u16*)alloc((size_t)D_ * D_ * 2);
    u16* w1T   = (u16*)alloc((size_t)DFF_ * D_ * 2);
    u16* w2T   = (u16*)alloc((size_t)D_ * DFF_ * 2);
    u32* mbits = (u32*)alloc((size_t)B_ * S_ * 64 * 4);
    u32* amsk  = (u32*)alloc((size_t)B_ * S_ * 4);
    u16* aout  = (u16*)alloc((size_t)M_ * D_ * 2);
    u16* yb    = (u16*)alloc((size_t)M_ * D_ * 2);     // WO out + resid, bf16
    u16* y0b   = (u16*)alloc((size_t)M_ * D_ * 2);     // FFN2 partial 0, bf16
    u16* y1b   = (u16*)alloc((size_t)M_ * D_ * 2);     // FFN2 partial 1, bf16
    u16* x1b   = (u16*)alloc((size_t)M_ * D_ * 2);     // LN1 out, bf16
    u16* vTb   = (u16*)alloc((size_t)64 * 64 * 2048 * 2);
    u16* qkv   = (u16*)alloc((size_t)M_ * DFF_ * 2);
    u16* hft   = qkv;

    // 1) fused pre-pass (2 launches)
    k_prep<<<dim3(2048 + (M_ * D_ / 4) / 256), 256, 0, stream>>>(msk, mbits, amsk, x, xb);
    k_wt<<<dim3(12288), 256, 0, stream>>>(wq, wk, wv, wo, w1, w2, wqkvT, w1T, w2T);

    // 2) QKV projection (128^2, 1536 blocks); V written transposed into vTb.
    k_gemm8<0><<<dim3(1536), 512, 0, stream>>>(xb, wqkvT, qkv, nullptr,
                                               nullptr, vTb, 3 * D_, D_);
    // 3) flash attention (8-wave, QBLK=256, 512 blocks)
    k_attn<<<dim3(8, 64), 512, 0, stream>>>(qkv, vTb, mbits, amsk, aout);
    // 4) output projection + bf16 residual -> yb (bf16)
    k_gemm8<1><<<dim3(512), 512, 0, stream>>>(aout, woT, yb, nullptr, xb,
                                              nullptr, D_, D_);
    // 5) LN1 (bf16 in/out)
    k_ln_b<<<dim3(M_), 256, 0, stream>>>(yb, x1b, a1, bt1);
    // 6) FFN1 (256^2 4-phase, 512 blocks)
    k_gemm256<2, 1><<<dim3(512), 512, 0, stream>>>(x1b, w1T, hft, nullptr,
                                                   b1, DFF_, D_, D_);
    // 7) FFN2 split-K=2 (256 blocks): bf16 partials y0b, y1b
    k_gemm256<3, 2><<<dim3(256), 512, 0, stream>>>(hft, w2T, y0b, y1b,
                                                   nullptr, D_, DFF_ / 2, DFF_);
    // 8) LN2 over (y0b + y1b + b2 + x1b) -> d_out
    k_ln_sum2<<<dim3(M_), 256, 0, stream>>>(y0b, y1b, x1b, b2, out, a2, bt2);
}